// Round 15
// baseline (161.046 us; speedup 1.0000x reference)
//
#include <hip/hip_runtime.h>
#include <math.h>

#define B_    4
#define S_    2048
#define BS_   8192       // B_*S_
#define DM_   1024
#define DS_   256
#define LB_   64
#define TOPK_ 8

typedef unsigned short u16;
typedef __bf16 bf16x8 __attribute__((ext_vector_type(8)));
typedef float  f32x4  __attribute__((ext_vector_type(4)));

static __device__ __forceinline__ u16 f2bf(float f) {
    union { float f; unsigned u; } a; a.f = f;
    unsigned u = a.u;
    unsigned r = u + 0x7FFFu + ((u >> 16) & 1u);   // RNE
    return (u16)(r >> 16);
}
static __device__ __forceinline__ float bf2f(u16 v) {
    union { unsigned u; float f; } a; a.u = ((unsigned)v) << 16; return a.f;
}
static __device__ __forceinline__ unsigned pack2(float a, float b) {
    return (unsigned)f2bf(a) | ((unsigned)f2bf(b) << 16);
}

// async global->LDS, 16B per lane; LDS dest = uniform base + lane*16
#define GLD16(g, l) __builtin_amdgcn_global_load_lds(                         \
    (const __attribute__((address_space(1))) void*)(g),                       \
    (__attribute__((address_space(3))) void*)(l), 16, 0, 0)

// ---------------------------------------------------------------------------
// Slab GEMM building blocks (BM=32, BN=64, K-slab=256, 48KB LDS -> 3 blk/CU).
// A slab: 32 rows x 512B (16KB); B slab: 64 rows x 512B (32KB).
// Granule swizzle g^(row&15); staging via global_load_lds with pre-swizzled
// source granule; fragment reads apply the same involution.
// Wave grid 2x2 over 32x64: wave tile 16x32 = 1(M) x 2(N) fragments.
// ---------------------------------------------------------------------------
__device__ __forceinline__ void slab_mfma1(
    unsigned char* smA, unsigned char* smB, f32x4 (&acc)[2],
    int wm, int wn, int lr, int lc)
{
    #pragma unroll
    for (int kg = 0; kg < 8; ++kg) {
        int m = wm * 16 + lr;
        bf16x8 af = *reinterpret_cast<const bf16x8*>(
            smA + m * 512 + (((kg * 4 + lc) ^ (m & 15)) * 16));
        #pragma unroll
        for (int j = 0; j < 2; ++j) {
            int n = wn * 32 + j * 16 + lr;
            bf16x8 bv = *reinterpret_cast<const bf16x8*>(
                smB + n * 512 + (((kg * 4 + lc) ^ (n & 15)) * 16));
            acc[j] = __builtin_amdgcn_mfma_f32_16x16x32_bf16(af, bv, acc[j], 0, 0, 0);
        }
    }
}

// stage A slab (32 rows, pitch pitchA u16) + B slab (64 rows, pitch pitchB)
__device__ __forceinline__ void slab_stage(
    unsigned char* smA, unsigned char* smB,
    const u16* __restrict__ Abase, int pitchA,
    const u16* __restrict__ Bbase, int pitchB,
    int wid, int lrow2, int g_lin)
{
    #pragma unroll
    for (int t = 0; t < 4; ++t) {
        int rbase = wid * 8 + t * 2;
        int row   = rbase + lrow2;
        int gg    = g_lin ^ (row & 15);
        GLD16(Abase + (size_t)row * pitchA + gg * 8, smA + (size_t)rbase * 512);
    }
    #pragma unroll
    for (int t = 0; t < 8; ++t) {
        int rbase = wid * 16 + t * 2;
        int row   = rbase + lrow2;
        int gg    = g_lin ^ (row & 15);
        GLD16(Bbase + (size_t)row * pitchB + gg * 8, smB + (size_t)rbase * 512);
    }
}

// ---------------------------------------------------------------------------
// Epilogue: EPI 0 -> C bf16 | 2 -> C bf16 = extra0_bf16 + val*extra1[m]
//           3 -> C f32 = extra0_bf16 + val.
// ---------------------------------------------------------------------------
template<int EPI>
__device__ __forceinline__ void epilogue1(
    f32x4 (&acc)[2], int bm, int bn, int wm, int wn, int lr, int lc,
    const float* __restrict__ bias, void* __restrict__ Cv, int N,
    const void* __restrict__ extra0v, const float* __restrict__ extra1)
{
    #pragma unroll
    for (int j = 0; j < 2; ++j) {
        int col = bn + wn * 32 + j * 16 + lr;
        #pragma unroll
        for (int r = 0; r < 4; ++r) {
            int row = bm + wm * 16 + lc * 4 + r;
            float val = acc[j][r] + bias[col];
            if constexpr (EPI == 2) {
                const u16* e0 = (const u16*)extra0v;
                val = bf2f(e0[(size_t)row * N + col]) + val * extra1[row];
                ((u16*)Cv)[(size_t)row * N + col] = f2bf(val);
            } else if constexpr (EPI == 3) {
                const u16* e0 = (const u16*)extra0v;
                ((float*)Cv)[(size_t)row * N + col] = bf2f(e0[(size_t)row * N + col]) + val;
            } else {
                ((u16*)Cv)[(size_t)row * N + col] = f2bf(val);
            }
        }
    }
}

// ---------------------------------------------------------------------------
// Single-stage K=256 GEMM: stage 48KB -> ONE barrier -> 16 MFMA/wave.
// ---------------------------------------------------------------------------
template<int EPI>
__device__ __forceinline__ void mm256_dev(
    unsigned char* smem, int id, int nb, int gx,
    const u16* __restrict__ A, const u16* __restrict__ Bt,
    const float* __restrict__ bias, void* __restrict__ Cv,
    int N, const void* __restrict__ extra0v, const float* __restrict__ extra1)
{
    unsigned char* smA = smem;
    unsigned char* smB = smem + 16384;

    const int per = nb >> 3;
    const int nid = (id & 7) * per + (id >> 3);   // bijective XCD chunking
    const int bx  = nid % gx, by = nid / gx;

    const int lane = threadIdx.x & 63, wid = threadIdx.x >> 6;
    const int wm   = wid >> 1, wn = wid & 1;
    const int bm   = by * 32, bn = bx * 64;
    const int lr   = lane & 15, lc = lane >> 4;
    const int lrow2 = lane >> 5;
    const int g_lin = lane & 31;

    slab_stage(smA, smB, A + (size_t)bm * 256, 256,
               Bt + (size_t)bn * 256, 256, wid, lrow2, g_lin);
    __syncthreads();

    f32x4 acc[2] = {};
    slab_mfma1(smA, smB, acc, wm, wn, lr, lc);

    epilogue1<EPI>(acc, bm, bn, wm, wn, lr, lc, bias, Cv, N, extra0v, extra1);
}

template<int EPI>
__global__ __launch_bounds__(256) void mm256_k(
    const u16* __restrict__ A, const u16* __restrict__ Bt,
    const float* __restrict__ bias, void* __restrict__ Cv,
    int N, int gx,
    const void* __restrict__ extra0v, const float* __restrict__ extra1)
{
    __shared__ __align__(16) unsigned char smem[49152];
    mm256_dev<EPI>(smem, blockIdx.x, gridDim.x, gx, A, Bt, bias, Cv, N,
                   extra0v, extra1);
}

// ---------------------------------------------------------------------------
// K=1024 GEMM as 4 sequential K=256 slabs. A pitch 1024, Bt pitch 1024.
// ---------------------------------------------------------------------------
template<int EPI>
__global__ __launch_bounds__(256) void mm1024_k(
    const u16* __restrict__ A, const u16* __restrict__ Bt,
    const float* __restrict__ bias, void* __restrict__ Cv,
    int N, int gx,
    const void* __restrict__ extra0v, const float* __restrict__ extra1)
{
    __shared__ __align__(16) unsigned char smem[49152];
    unsigned char* smA = smem;
    unsigned char* smB = smem + 16384;

    const int nb  = gridDim.x;
    const int per = nb >> 3;
    const int id  = blockIdx.x;
    const int nid = (id & 7) * per + (id >> 3);
    const int bx  = nid % gx, by = nid / gx;

    const int lane = threadIdx.x & 63, wid = threadIdx.x >> 6;
    const int wm   = wid >> 1, wn = wid & 1;
    const int bm   = by * 32, bn = bx * 64;
    const int lr   = lane & 15, lc = lane >> 4;
    const int lrow2 = lane >> 5;
    const int g_lin = lane & 31;

    f32x4 acc[2] = {};

    #pragma unroll
    for (int s = 0; s < 4; ++s) {
        if (s) __syncthreads();
        slab_stage(smA, smB, A + (size_t)bm * 1024 + s * 256, 1024,
                   Bt + (size_t)bn * 1024 + s * 256, 1024, wid, lrow2, g_lin);
        __syncthreads();
        slab_mfma1(smA, smB, acc, wm, wn, lr, lc);
    }

    epilogue1<EPI>(acc, bm, bn, wm, wn, lr, lc, bias, Cv, N, extra0v, extra1);
}

// ---------------------------------------------------------------------------
// ui-concat GEMM + tanh: 4 slabs, slab s's A = segment s (h|mixed|php|summ).
// ---------------------------------------------------------------------------
__global__ __launch_bounds__(256) void mm_ui_k(
    const u16* __restrict__ h, const u16* __restrict__ mixed,
    const u16* __restrict__ php, const u16* __restrict__ summ,
    const u16* __restrict__ W1t, const float* __restrict__ b1,
    u16* __restrict__ t)
{
    __shared__ __align__(16) unsigned char smem[49152];
    unsigned char* smA = smem;
    unsigned char* smB = smem + 16384;

    const int nb  = gridDim.x;
    const int per = nb >> 3;
    const int id  = blockIdx.x;
    const int nid = (id & 7) * per + (id >> 3);
    const int bx  = nid & 3, by = nid >> 2;

    const int lane = threadIdx.x & 63, wid = threadIdx.x >> 6;
    const int wm   = wid >> 1, wn = wid & 1;
    const int bm   = by * 32, bn = bx * 64;
    const int lr   = lane & 15, lc = lane >> 4;
    const int lrow2 = lane >> 5;
    const int g_lin = lane & 31;

    f32x4 acc[2] = {};

    #pragma unroll
    for (int s = 0; s < 4; ++s) {
        const u16* Asrc = (s == 0) ? h : (s == 1) ? mixed : (s == 2) ? php : summ;
        if (s) __syncthreads();
        // A: php segment uses pooled rows (rs = (bm+row)>>4)
        #pragma unroll
        for (int tt = 0; tt < 4; ++tt) {
            int rbase = wid * 8 + tt * 2;
            int row   = rbase + lrow2;
            int gg    = g_lin ^ (row & 15);
            int rs    = bm + row;
            if (s == 2) rs >>= 4;
            GLD16(Asrc + (size_t)rs * 256 + gg * 8, smA + (size_t)rbase * 512);
        }
        #pragma unroll
        for (int tt = 0; tt < 8; ++tt) {
            int rbase = wid * 16 + tt * 2;
            int row   = rbase + lrow2;
            int gg    = g_lin ^ (row & 15);
            GLD16(W1t + (size_t)(bn + row) * 1024 + s * 256 + gg * 8,
                  smB + (size_t)rbase * 512);
        }
        __syncthreads();
        slab_mfma1(smA, smB, acc, wm, wn, lr, lc);
    }

    #pragma unroll
    for (int j = 0; j < 2; ++j) {
        int col = bn + wn * 32 + j * 16 + lr;
        #pragma unroll
        for (int r = 0; r < 4; ++r) {
            int row = bm + wm * 16 + lc * 4 + r;
            t[(size_t)row * DS_ + col] = f2bf(tanhf(acc[j][r] + b1[col]));
        }
    }
}

// ---------------------------------------------------------------------------
// Causal depthwise conv (K=5) + chunk mean + halt gate + fused php projection.
// ---------------------------------------------------------------------------
__device__ __forceinline__ void conv_dev(
    unsigned char* smem, int cid,
    const u16* __restrict__ h, const float* __restrict__ conv_w,
    const float* __restrict__ conv_b, const float* __restrict__ Wh,
    const float* __restrict__ bh, const u16* __restrict__ Wpt,
    const float* __restrict__ bp, u16* __restrict__ mixed,
    u16* __restrict__ php, float* __restrict__ gate)
{
    float* gpart = (float*)smem;            // [16][4]
    float* cm    = (float*)(smem + 256);    // [256]
    const int blk = (cid & 7) * 64 + (cid >> 3);   // XCD swizzle (8 x 64)
    const int d = threadIdx.x;
    const int b = blk >> 7;
    const int s0 = (blk & 127) * 16;
    const u16* hb = h + (size_t)b * S_ * DS_;
    u16* mb = mixed + (size_t)b * S_ * DS_;

    const float w0 = conv_w[0 * DS_ + d], w1 = conv_w[1 * DS_ + d],
                w2 = conv_w[2 * DS_ + d], w3 = conv_w[3 * DS_ + d],
                w4 = conv_w[4 * DS_ + d];
    const float cb = conv_b[d];
    const float whd = Wh[d * 3 + 2];

    float a0 = (s0 >= 4) ? bf2f(hb[(size_t)(s0 - 4) * DS_ + d]) : 0.f;
    float a1 = (s0 >= 3) ? bf2f(hb[(size_t)(s0 - 3) * DS_ + d]) : 0.f;
    float a2 = (s0 >= 2) ? bf2f(hb[(size_t)(s0 - 2) * DS_ + d]) : 0.f;
    float a3 = (s0 >= 1) ? bf2f(hb[(size_t)(s0 - 1) * DS_ + d]) : 0.f;

    float sum = 0.f;
    #pragma unroll
    for (int tt = 0; tt < 16; ++tt) {
        int s = s0 + tt;
        float cur = bf2f(hb[(size_t)s * DS_ + d]);
        mb[(size_t)s * DS_ + d] = f2bf(w0 * a0 + w1 * a1 + w2 * a2 + w3 * a3 + w4 * cur + cb);
        sum += cur;
        float g = cur * whd;
        #pragma unroll
        for (int off = 32; off; off >>= 1) g += __shfl_down(g, off);
        if ((d & 63) == 0) gpart[tt * 4 + (d >> 6)] = g;
        a0 = a1; a1 = a2; a2 = a3; a3 = cur;
    }
    cm[d] = sum * (1.f / 16.f);
    __syncthreads();
    if (d < 16) {
        float gg = gpart[d * 4 + 0] + gpart[d * 4 + 1] + gpart[d * 4 + 2] + gpart[d * 4 + 3];
        gate[(size_t)b * S_ + s0 + d] = 1.f / (1.f + expf(-(gg + bh[2])));
    }
    float accp = bp[d];
    const u16* wr = Wpt + (size_t)d * 256;
    #pragma unroll
    for (int k = 0; k < 256; k += 8) {
        bf16x8 w8 = *reinterpret_cast<const bf16x8*>(wr + k);
        accp += cm[k]     * (float)w8[0] + cm[k + 1] * (float)w8[1]
              + cm[k + 2] * (float)w8[2] + cm[k + 3] * (float)w8[3]
              + cm[k + 4] * (float)w8[4] + cm[k + 5] * (float)w8[5]
              + cm[k + 6] * (float)w8[6] + cm[k + 7] * (float)w8[7];
    }
    php[(size_t)blk * DS_ + d] = f2bf(accp);
}

// ---------------------------------------------------------------------------
// Packed launch: blocks 0..3071 qkv GEMM (BM=32, N=768); 3072..3583 conv+php.
// ---------------------------------------------------------------------------
__global__ __launch_bounds__(256) void step_a_k(
    const u16* __restrict__ h, const u16* __restrict__ Wqkvt,
    const float* __restrict__ bqkv, u16* __restrict__ qkv,
    const float* __restrict__ conv_w, const float* __restrict__ conv_b,
    const float* __restrict__ Wh, const float* __restrict__ bh,
    const u16* __restrict__ Wpt, const float* __restrict__ bp,
    u16* __restrict__ mixed, u16* __restrict__ php, float* __restrict__ gate)
{
    __shared__ __align__(16) unsigned char smem[49152];
    if (blockIdx.x < 3072) {
        mm256_dev<0>(smem, blockIdx.x, 3072, 12, h, Wqkvt, bqkv, qkv,
                     768, nullptr, nullptr);
    } else {
        conv_dev(smem, blockIdx.x - 3072, h, conv_w, conv_b, Wh, bh,
                 Wpt, bp, mixed, php, gate);
    }
}

// ---------------------------------------------------------------------------
// Banded scores via MFMA, single-stage (3 barriers total).
// ---------------------------------------------------------------------------
__global__ __launch_bounds__(256) void scores_k(
    const u16* __restrict__ qkv, float* __restrict__ scores)
{
    __shared__ __align__(16) unsigned char smem[65536];  // Q 16KB | K 48KB
    unsigned char* smQ = smem;
    unsigned char* smK = smem + 16384;
    float* Sld = reinterpret_cast<float*>(smem);         // [32][97], aliases Q

    const int bid = blockIdx.x;                    // 256 blocks
    const int blk = (bid & 7) * 32 + (bid >> 3);   // XCD swizzle (8 x 32)
    const int t0 = blk * 32;
    const int b  = t0 >> 11;
    const int s0 = t0 & (S_ - 1);
    const int tid = threadIdx.x;
    const int lane = tid & 63, wid = tid >> 6;
    const int lr = lane & 15, lc = lane >> 4;
    const int qt  = wid & 1;
    const int ktb = (wid >> 1) * 3;
    const int lrow2 = lane >> 5;
    const int g_lin = lane & 31;

    #pragma unroll
    for (int t = 0; t < 4; ++t) {
        int rbase = wid * 8 + t * 2;
        int row   = rbase + lrow2;
        int gg    = g_lin ^ (row & 15);
        GLD16(qkv + (size_t)(t0 + row) * 768 + gg * 8,
              smQ + (size_t)rbase * 512);
    }
    #pragma unroll
    for (int t = 0; t < 12; ++t) {
        int rbase = wid * 24 + t * 2;
        int row   = rbase + lrow2;
        int krow  = s0 - 64 + row; if (krow < 0) krow = 0;
        int gg    = g_lin ^ (row & 15);
        GLD16(qkv + ((size_t)(b * S_) + krow) * 768 + 256 + gg * 8,
              smK + (size_t)rbase * 512);
    }
    __syncthreads();

    f32x4 acc[3] = {};
    #pragma unroll
    for (int ks = 0; ks < 8; ++ks) {
        int m = qt * 16 + lr;
        bf16x8 af = *reinterpret_cast<const bf16x8*>(
            smQ + m * 512 + (((ks * 4 + lc) ^ (m & 15)) * 16));
        #pragma unroll
        for (int j = 0; j < 3; ++j) {
            int n = (ktb + j) * 16 + lr;
            bf16x8 bv = *reinterpret_cast<const bf16x8*>(
                smK + n * 512 + (((ks * 4 + lc) ^ (n & 15)) * 16));
            acc[j] = __builtin_amdgcn_mfma_f32_16x16x32_bf16(af, bv, acc[j], 0, 0, 0);
        }
    }
    __syncthreads();

    #pragma unroll
    for (int j = 0; j < 3; ++j) {
        int col = (ktb + j) * 16 + lr;
        #pragma unroll
        for (int r = 0; r < 4; ++r) {
            int row = qt * 16 + lc * 4 + r;
            Sld[row * 97 + col] = acc[j][r];
        }
    }
    __syncthreads();

    #pragma unroll
    for (int it = 0; it < 8; ++it) {
        int e = tid + it * 256;
        int i = e >> 6, l = e & 63;
        scores[(size_t)(t0 + i) * 64 + l] = Sld[i * 97 + i + l] * 0.0625f;
    }
}

// ---------------------------------------------------------------------------
// Top-8 select + softmax + V-sum. Top-8 via 64-lane bitonic sort
// (key = value desc, index asc -- identical order to jax.lax.top_k).
// ---------------------------------------------------------------------------
__global__ __launch_bounds__(256) void select_k(
    const float* __restrict__ scores, const u16* __restrict__ qkv,
    u16* __restrict__ summ)
{
    const int bid = blockIdx.x;                       // 2048 blocks
    const int sb  = (bid & 7) * 256 + (bid >> 3);     // bijective XCD swizzle
    const int m   = sb * 4 + (threadIdx.x >> 6);
    const int b = m >> 11;
    const int s = m & (S_ - 1);
    const int lane = threadIdx.x & 63;

    float v = (s - LB_ + lane >= 0) ? scores[(size_t)m * 64 + lane] : -INFINITY;
    int idx = lane;

    #pragma unroll
    for (int k = 2; k <= 64; k <<= 1) {
        #pragma unroll
        for (int j = k >> 1; j > 0; j >>= 1) {
            float ov = __shfl_xor(v, j);
            int   oi = __shfl_xor(idx, j);
            bool mineFirst = (v > ov) || (v == ov && idx < oi);
            bool lowLane  = (lane & j) == 0;
            bool dirFirst = (lane & k) == 0;
            bool keep = (lowLane == dirFirst) ? mineFirst : !mineFirst;
            if (!keep) { v = ov; idx = oi; }
        }
    }

    float vals[TOPK_]; int idxs[TOPK_];
    #pragma unroll
    for (int t = 0; t < TOPK_; ++t) {
        vals[t] = __shfl(v, t);
        idxs[t] = __shfl(idx, t);
    }

    const float mref = (vals[0] == -INFINITY) ? 0.f : vals[0];
    float e[TOPK_], ssum = 0.f;
    #pragma unroll
    for (int t = 0; t < TOPK_; ++t) { e[t] = expf(vals[t] - mref); ssum += e[t]; }
    const float inv = 1.f / fmaxf(ssum, 1e-30f);

    float o0 = 0.f, o1 = 0.f, o2 = 0.f, o3 = 0.f;
    #pragma unroll
    for (int t = 0; t < TOPK_; ++t) {
        float wt = e[t] * inv;
        int tok = s - LB_ + idxs[t];
        tok = min(max(tok, 0), S_ - 1);
        ushort4 vv = *reinterpret_cast<const ushort4*>(
            qkv + ((size_t)(b * S_) + tok) * 768 + 512 + lane * 4);
        o0 += wt * bf2f(vv.x);
        o1 += wt * bf2f(vv.y);
        o2 += wt * bf2f(vv.z);
        o3 += wt * bf2f(vv.w);
    }
    ushort4 pk;
    pk.x = f2bf(o0); pk.y = f2bf(o1); pk.z = f2bf(o2); pk.w = f2bf(o3);
    *reinterpret_cast<ushort4*>(summ + (size_t)m * DS_ + lane * 4) = pk;
}

// ---------------------------------------------------------------------------
// Merged prep: blocks 0..4095 cvt x->bf16; 4096..5183 weight transposes;
// 5184 qkv bias concat.
// ---------------------------------------------------------------------------
__global__ __launch_bounds__(256) void prep_all_k(
    const float* __restrict__ x,
    const float* __restrict__ Wi, const float* __restrict__ Wq,
    const float* __restrict__ Wk, const float* __restrict__ Wv,
    const float* __restrict__ Wp, const float* __restrict__ W1,
    const float* __restrict__ W2, const float* __restrict__ Wo,
    const float* __restrict__ bq, const float* __restrict__ bk,
    const float* __restrict__ bv,
    u16* __restrict__ xb,
    u16* __restrict__ Wit, u16* __restrict__ Wqkvt, u16* __restrict__ Wpt,
    u16* __restrict__ W1t, u16* __restrict__ W2t, u16* __restrict__ Wot,
    float* __restrict__ bqkv)
{
    const int bid0 = blockIdx.x;
    if (bid0 < 4096) {
        int i = (bid0 * 256 + threadIdx.x) * 8;
        float4 a = *reinterpret_cast<const float4*>(x + i);
        float4 b = *reinterpret_cast<const float4*>(x + i + 4);
        uint4 g;
        g.x = pack2(a.x, a.y); g.y = pack2(a.z, a.w);
        g.z = pack2(b.x, b.y); g.w = pack2(b.z, b.w);
        *reinterpret_cast<uint4*>(xb + i) = g;
        return;
    }
    const int bid = bid0 - 4096;
    if (bid >= 1088) {
        for (int i = threadIdx.x; i < 768; i += 256) {
            float v = (i < 256) ? bq[i] : (i < 512) ? bk[i - 256] : bv[i - 512];
            bqkv[i] = v;
        }
        return;
    }
    const float* in; u16* out; int K, N, t;
    if (bid < 256)      { in = Wi; out = Wit;             K = 1024; N = 256;  t = bid; }
    else if (bid < 320) { in = Wq; out = Wqkvt;           K = 256;  N = 256;  t = bid - 256; }
    else if (bid < 384) { in = Wk; out = Wqkvt + 256*256; K = 256;  N = 256;  t = bid - 320; }
    else if (bid < 448) { in = Wv; out = Wqkvt + 512*256; K = 256;  N = 256;  t = bid - 384; }
    else if (bid < 512) { in = Wp; out = Wpt;             K = 256;  N = 256;  t = bid - 448; }
    else if (bid < 768) { in = W1; out = W1t;             K = 1024; N = 256;  t = bid - 512; }
    else if (bid < 832) { in = W2; out = W2t;             K = 256;  N = 256;  t = bid - 768; }
    else                { in = Wo; out = Wot;             K = 256;  N = 1024; t = bid - 832; }
    const int tilesX = N >> 5;
    const int n0 = (t % tilesX) * 32, k0 = (t / tilesX) * 32;
    __shared__ float tl[32][33];
    const int cx = threadIdx.x & 31, cy = threadIdx.x >> 5;
    #pragma unroll
    for (int r = 0; r < 32; r += 8)
        tl[cy + r][cx] = in[(size_t)(k0 + cy + r) * N + n0 + cx];
    __syncthreads();
    #pragma unroll
    for (int r = 0; r < 32; r += 8)
        out[(size_t)(n0 + cy + r) * K + k0 + cx] = f2bf(tl[cx][cy + r]);
}

// ---------------------------------------------------------------------------
extern "C" void kernel_launch(void* const* d_in, const int* in_sizes, int n_in,
                              void* d_out, int out_size, void* d_ws, size_t ws_size,
                              hipStream_t stream)
{
    const float* x      = (const float*)d_in[0];
    const float* Wi     = (const float*)d_in[1];
    const float* bi     = (const float*)d_in[2];
    const float* conv_w = (const float*)d_in[3];
    const float* conv_b = (const float*)d_in[4];
    const float* Wp     = (const float*)d_in[5];
    const float* bp     = (const float*)d_in[6];
    const float* Wh     = (const float*)d_in[7];
    const float* bh     = (const float*)d_in[8];
    const float* Wq     = (const float*)d_in[9];
    const float* bq     = (const float*)d_in[10];
    const float* Wk     = (const float*)d_in[11];
    const float* bk     = (const float*)d_in[12];
    const float* Wv     = (const float*)d_in[13];
    const float* bv     = (const float*)d_in[14];
    const float* W1     = (const float*)d_in[15];
    const float* b1     = (const float*)d_in[16];
    const float* W2     = (const float*)d_in[17];
    const float* b2     = (const float*)d_in[18];
    const float* Wo     = (const float*)d_in[19];
    const float* bo     = (const float*)d_in[20];
    float* out = (float*)d_out;

    char* p = (char*)d_ws;
    auto alloc = [&](size_t bytes) { char* r = p; p += (bytes + 255) & ~(size_t)255; return r; };

    u16*  xb     = (u16*)alloc((size_t)BS_ * DM_ * 2);
    u16*  h      = (u16*)alloc((size_t)BS_ * DS_ * 2);
    u16*  mixed  = (u16*)alloc((size_t)BS_ * DS_ * 2);
    u16*  qkv    = (u16*)alloc((size_t)BS_ * 768 * 2);
    u16*  sm     = (u16*)alloc((size_t)BS_ * DS_ * 2);
    u16*  tb     = (u16*)alloc((size_t)BS_ * DS_ * 2);
    u16*  php    = (u16*)alloc((size_t)512 * DS_ * 2);
    float* gate  = (float*)alloc((size_t)BS_ * 4);
    float* scores= (float*)alloc((size_t)BS_ * 64 * 4);
    float* bqkv  = (float*)alloc(768 * 4);
    u16* Wit     = (u16*)alloc((size_t)256 * 1024 * 2);
    u16* Wqkvt   = (u16*)alloc((size_t)768 * 256 * 2);
    u16* Wpt     = (u16*)alloc((size_t)256 * 256 * 2);
    u16* W1t     = (u16*)alloc((size_t)256 * 1024 * 2);
    u16* W2t     = (u16*)alloc((size_t)256 * 256 * 2);
    u16* Wot     = (u16*)alloc((size_t)1024 * 256 * 2);

    dim3 blk(256);

    // ---- prep (cvt x + all weight transposes + bias concat) ----
    prep_all_k<<<5185, blk, 0, stream>>>(x, Wi, Wq, Wk, Wv, Wp, W1, W2, Wo,
                                         bq, bk, bv, xb,
                                         Wit, Wqkvt, Wpt, W1t, W2t, Wot, bqkv);

    // ---- forward ----
    // h = x @ Wi + bi   (K=1024 as 4 slabs; BM=32, grid 4x256)
    mm1024_k<0><<<1024, blk, 0, stream>>>(xb, Wit, bi, h, DS_, 4, nullptr, nullptr);

    for (int step = 0; step < 2; ++step) {
        // packed: qkv GEMM (3072 blocks, BM=32) + conv/pool/gate/php (512)
        step_a_k<<<3584, blk, 0, stream>>>(h, Wqkvt, bqkv, qkv,
                                           conv_w, conv_b, Wh, bh, Wpt, bp,
                                           mixed, php, gate);
        scores_k<<<256, blk, 0, stream>>>(qkv, scores);
        select_k<<<2048, blk, 0, stream>>>(scores, qkv, sm);
        mm_ui_k<<<1024, blk, 0, stream>>>(h, mixed, php, sm, W1t, b1, tb);
        // h = h + (tanh(ui@W1+b1) @ W2 + b2) * gate
        mm256_k<2><<<1024, blk, 0, stream>>>(tb, W2t, b2, h, DS_, 4, h, gate);
    }

    // out = x + h @ Wo + bo
    mm256_k<3><<<4096, blk, 0, stream>>>(h, Wot, bo, out, DM_, 16, xb, nullptr);
}

// Round 16
// 140.853 us; speedup vs baseline: 1.1434x; 1.1434x over previous
//
#include <hip/hip_runtime.h>
#include <math.h>

#define B_    4
#define S_    2048
#define BS_   8192       // B_*S_
#define DM_   1024
#define DS_   256
#define LB_   64
#define TOPK_ 8

typedef unsigned short u16;
typedef __bf16 bf16x8 __attribute__((ext_vector_type(8)));
typedef float  f32x4  __attribute__((ext_vector_type(4)));

static __device__ __forceinline__ u16 f2bf(float f) {
    union { float f; unsigned u; } a; a.f = f;
    unsigned u = a.u;
    unsigned r = u + 0x7FFFu + ((u >> 16) & 1u);   // RNE
    return (u16)(r >> 16);
}
static __device__ __forceinline__ float bf2f(u16 v) {
    union { unsigned u; float f; } a; a.u = ((unsigned)v) << 16; return a.f;
}
static __device__ __forceinline__ unsigned pack2(float a, float b) {
    return (unsigned)f2bf(a) | ((unsigned)f2bf(b) << 16);
}

// async global->LDS, 16B per lane; LDS dest = uniform base + lane*16
#define GLD16(g, l) __builtin_amdgcn_global_load_lds(                         \
    (const __attribute__((address_space(1))) void*)(g),                       \
    (__attribute__((address_space(3))) void*)(l), 16, 0, 0)

// ---------------------------------------------------------------------------
// Epilogue: EPI 0 -> C bf16 | 2 -> C bf16 = extra0_bf16 + val*extra1[m]
//           3 -> C f32 = extra0_bf16 + val.
// ---------------------------------------------------------------------------
template<int MF, int EPI>
__device__ __forceinline__ void epilogue(
    f32x4 (&acc)[MF][2], int bm, int bn, int wm, int wn, int lr, int lc,
    const float* __restrict__ bias, void* __restrict__ Cv, int N,
    const void* __restrict__ extra0v, const float* __restrict__ extra1)
{
    #pragma unroll
    for (int i = 0; i < MF; ++i) {
        #pragma unroll
        for (int j = 0; j < 2; ++j) {
            int col = bn + wn * 32 + j * 16 + lr;
            #pragma unroll
            for (int r = 0; r < 4; ++r) {
                int row = bm + wm * (MF * 16) + i * 16 + lc * 4 + r;
                float val = acc[i][j][r] + bias[col];
                if constexpr (EPI == 2) {
                    const u16* e0 = (const u16*)extra0v;
                    val = bf2f(e0[(size_t)row * N + col]) + val * extra1[row];
                    ((u16*)Cv)[(size_t)row * N + col] = f2bf(val);
                } else if constexpr (EPI == 3) {
                    const u16* e0 = (const u16*)extra0v;
                    ((float*)Cv)[(size_t)row * N + col] = bf2f(e0[(size_t)row * N + col]) + val;
                } else {
                    ((u16*)Cv)[(size_t)row * N + col] = f2bf(val);
                }
            }
        }
    }
}

// ---------------------------------------------------------------------------
// Shared compute: 32 MFMAs/wave over a staged 64x256 A-slab + 64x256 B-slab.
// LDS rows 512B (32 granules of 16B), granule swizzle g^(row&15).
// ---------------------------------------------------------------------------
__device__ __forceinline__ void slab_mfma(
    unsigned char* smA, unsigned char* smB, f32x4 (&acc)[2][2],
    int wm, int wn, int lr, int lc)
{
    #pragma unroll
    for (int kg = 0; kg < 8; ++kg) {
        bf16x8 af[2], bfr[2];
        #pragma unroll
        for (int i = 0; i < 2; ++i) {
            int m = wm * 32 + i * 16 + lr;
            af[i] = *reinterpret_cast<const bf16x8*>(
                smA + m * 512 + (((kg * 4 + lc) ^ (m & 15)) * 16));
        }
        #pragma unroll
        for (int j = 0; j < 2; ++j) {
            int n = wn * 32 + j * 16 + lr;
            bfr[j] = *reinterpret_cast<const bf16x8*>(
                smB + n * 512 + (((kg * 4 + lc) ^ (n & 15)) * 16));
        }
        #pragma unroll
        for (int i = 0; i < 2; ++i)
            #pragma unroll
            for (int j = 0; j < 2; ++j)
                acc[i][j] = __builtin_amdgcn_mfma_f32_16x16x32_bf16(
                    af[i], bfr[j], acc[i][j], 0, 0, 0);
    }
}

// ---------------------------------------------------------------------------
// Single-stage full-K GEMM for K=256: stage 64KB -> ONE barrier -> 32 MFMA.
// ---------------------------------------------------------------------------
template<int EPI>
__device__ __forceinline__ void mm256_dev(
    unsigned char* smem, int id, int nb, int gx,
    const u16* __restrict__ A, const u16* __restrict__ Bt,
    const float* __restrict__ bias, void* __restrict__ Cv,
    int N, const void* __restrict__ extra0v, const float* __restrict__ extra1)
{
    unsigned char* smA = smem;
    unsigned char* smB = smem + 32768;

    const int per = nb >> 3;
    const int nid = (id & 7) * per + (id >> 3);   // bijective XCD chunking
    const int bx  = nid % gx, by = nid / gx;

    const int lane = threadIdx.x & 63, wid = threadIdx.x >> 6;
    const int wm   = wid >> 1, wn = wid & 1;
    const int bm   = by * 64, bn = bx * 64;
    const int lr   = lane & 15, lc = lane >> 4;
    const int lrow2 = lane >> 5;
    const int g_lin = lane & 31;

    #pragma unroll
    for (int t = 0; t < 8; ++t) {
        int rbase = wid * 16 + t * 2;
        int row   = rbase + lrow2;
        int gg    = g_lin ^ (row & 15);
        GLD16(A + (size_t)(bm + row) * 256 + gg * 8, smA + (size_t)rbase * 512);
    }
    #pragma unroll
    for (int t = 0; t < 8; ++t) {
        int rbase = wid * 16 + t * 2;
        int row   = rbase + lrow2;
        int gg    = g_lin ^ (row & 15);
        GLD16(Bt + (size_t)(bn + row) * 256 + gg * 8, smB + (size_t)rbase * 512);
    }
    __syncthreads();

    f32x4 acc[2][2] = {};
    slab_mfma(smA, smB, acc, wm, wn, lr, lc);

    epilogue<2, EPI>(acc, bm, bn, wm, wn, lr, lc, bias, Cv, N, extra0v, extra1);
}

template<int EPI>
__global__ __launch_bounds__(256) void mm256_k(
    const u16* __restrict__ A, const u16* __restrict__ Bt,
    const float* __restrict__ bias, void* __restrict__ Cv,
    int N, int gx,
    const void* __restrict__ extra0v, const float* __restrict__ extra1)
{
    __shared__ __align__(16) unsigned char smem[65536];
    mm256_dev<EPI>(smem, blockIdx.x, gridDim.x, gx, A, Bt, bias, Cv, N,
                   extra0v, extra1);
}

// ---------------------------------------------------------------------------
// K=1024 GEMM as 4 sequential single-stage K=256 slabs (7 barriers total).
// A pitch 1024 (xb), Bt pitch 1024. Used for Wi.
// ---------------------------------------------------------------------------
template<int EPI>
__global__ __launch_bounds__(256) void mm1024_k(
    const u16* __restrict__ A, const u16* __restrict__ Bt,
    const float* __restrict__ bias, void* __restrict__ Cv,
    int N, int gx,
    const void* __restrict__ extra0v, const float* __restrict__ extra1)
{
    __shared__ __align__(16) unsigned char smem[65536];
    unsigned char* smA = smem;
    unsigned char* smB = smem + 32768;

    const int nb  = gridDim.x;
    const int per = nb >> 3;
    const int id  = blockIdx.x;
    const int nid = (id & 7) * per + (id >> 3);
    const int bx  = nid % gx, by = nid / gx;

    const int lane = threadIdx.x & 63, wid = threadIdx.x >> 6;
    const int wm   = wid >> 1, wn = wid & 1;
    const int bm   = by * 64, bn = bx * 64;
    const int lr   = lane & 15, lc = lane >> 4;
    const int lrow2 = lane >> 5;
    const int g_lin = lane & 31;

    f32x4 acc[2][2] = {};

    #pragma unroll
    for (int s = 0; s < 4; ++s) {
        if (s) __syncthreads();   // previous slab's reads complete
        #pragma unroll
        for (int t = 0; t < 8; ++t) {
            int rbase = wid * 16 + t * 2;
            int row   = rbase + lrow2;
            int gg    = g_lin ^ (row & 15);
            GLD16(A + (size_t)(bm + row) * 1024 + s * 256 + gg * 8,
                  smA + (size_t)rbase * 512);
        }
        #pragma unroll
        for (int t = 0; t < 8; ++t) {
            int rbase = wid * 16 + t * 2;
            int row   = rbase + lrow2;
            int gg    = g_lin ^ (row & 15);
            GLD16(Bt + (size_t)(bn + row) * 1024 + s * 256 + gg * 8,
                  smB + (size_t)rbase * 512);
        }
        __syncthreads();
        slab_mfma(smA, smB, acc, wm, wn, lr, lc);
    }

    epilogue<2, EPI>(acc, bm, bn, wm, wn, lr, lc, bias, Cv, N, extra0v, extra1);
}

// ---------------------------------------------------------------------------
// ui-concat GEMM + tanh as 4 slabs; slab s's A-source = concat segment s
// (h | mixed | php(pool rows) | summ).
// ---------------------------------------------------------------------------
__global__ __launch_bounds__(256) void mm_ui_k(
    const u16* __restrict__ h, const u16* __restrict__ mixed,
    const u16* __restrict__ php, const u16* __restrict__ summ,
    const u16* __restrict__ W1t, const float* __restrict__ b1,
    u16* __restrict__ t)
{
    __shared__ __align__(16) unsigned char smem[65536];
    unsigned char* smA = smem;
    unsigned char* smB = smem + 32768;

    const int nb  = gridDim.x;
    const int per = nb >> 3;
    const int id  = blockIdx.x;
    const int nid = (id & 7) * per + (id >> 3);
    const int bx  = nid & 3, by = nid >> 2;

    const int lane = threadIdx.x & 63, wid = threadIdx.x >> 6;
    const int wm   = wid >> 1, wn = wid & 1;
    const int bm   = by * 64, bn = bx * 64;
    const int lr   = lane & 15, lc = lane >> 4;
    const int lrow2 = lane >> 5;
    const int g_lin = lane & 31;

    f32x4 acc[2][2] = {};

    #pragma unroll
    for (int s = 0; s < 4; ++s) {
        const u16* Asrc = (s == 0) ? h : (s == 1) ? mixed : (s == 2) ? php : summ;
        if (s) __syncthreads();
        #pragma unroll
        for (int tt = 0; tt < 8; ++tt) {
            int rbase = wid * 16 + tt * 2;
            int row   = rbase + lrow2;
            int gg    = g_lin ^ (row & 15);
            int rs    = bm + row;
            if (s == 2) rs >>= 4;
            GLD16(Asrc + (size_t)rs * 256 + gg * 8, smA + (size_t)rbase * 512);
        }
        #pragma unroll
        for (int tt = 0; tt < 8; ++tt) {
            int rbase = wid * 16 + tt * 2;
            int row   = rbase + lrow2;
            int gg    = g_lin ^ (row & 15);
            GLD16(W1t + (size_t)(bn + row) * 1024 + s * 256 + gg * 8,
                  smB + (size_t)rbase * 512);
        }
        __syncthreads();
        slab_mfma(smA, smB, acc, wm, wn, lr, lc);
    }

    #pragma unroll
    for (int i = 0; i < 2; ++i) {
        #pragma unroll
        for (int j = 0; j < 2; ++j) {
            int col = bn + wn * 32 + j * 16 + lr;
            #pragma unroll
            for (int r = 0; r < 4; ++r) {
                int row = bm + wm * 32 + i * 16 + lc * 4 + r;
                t[(size_t)row * DS_ + col] = f2bf(tanhf(acc[i][j][r] + b1[col]));
            }
        }
    }
}

// ---------------------------------------------------------------------------
// Causal depthwise conv (K=5) + chunk mean + halt gate + fused php projection.
// ---------------------------------------------------------------------------
__device__ __forceinline__ void conv_dev(
    unsigned char* smem, int cid,
    const u16* __restrict__ h, const float* __restrict__ conv_w,
    const float* __restrict__ conv_b, const float* __restrict__ Wh,
    const float* __restrict__ bh, const u16* __restrict__ Wpt,
    const float* __restrict__ bp, u16* __restrict__ mixed,
    u16* __restrict__ php, float* __restrict__ gate)
{
    float* gpart = (float*)smem;            // [16][4]
    float* cm    = (float*)(smem + 256);    // [256]
    const int blk = (cid & 7) * 64 + (cid >> 3);   // XCD swizzle (8 x 64)
    const int d = threadIdx.x;
    const int b = blk >> 7;
    const int s0 = (blk & 127) * 16;
    const u16* hb = h + (size_t)b * S_ * DS_;
    u16* mb = mixed + (size_t)b * S_ * DS_;

    const float w0 = conv_w[0 * DS_ + d], w1 = conv_w[1 * DS_ + d],
                w2 = conv_w[2 * DS_ + d], w3 = conv_w[3 * DS_ + d],
                w4 = conv_w[4 * DS_ + d];
    const float cb = conv_b[d];
    const float whd = Wh[d * 3 + 2];

    float a0 = (s0 >= 4) ? bf2f(hb[(size_t)(s0 - 4) * DS_ + d]) : 0.f;
    float a1 = (s0 >= 3) ? bf2f(hb[(size_t)(s0 - 3) * DS_ + d]) : 0.f;
    float a2 = (s0 >= 2) ? bf2f(hb[(size_t)(s0 - 2) * DS_ + d]) : 0.f;
    float a3 = (s0 >= 1) ? bf2f(hb[(size_t)(s0 - 1) * DS_ + d]) : 0.f;

    float sum = 0.f;
    #pragma unroll
    for (int tt = 0; tt < 16; ++tt) {
        int s = s0 + tt;
        float cur = bf2f(hb[(size_t)s * DS_ + d]);
        mb[(size_t)s * DS_ + d] = f2bf(w0 * a0 + w1 * a1 + w2 * a2 + w3 * a3 + w4 * cur + cb);
        sum += cur;
        float g = cur * whd;
        #pragma unroll
        for (int off = 32; off; off >>= 1) g += __shfl_down(g, off);
        if ((d & 63) == 0) gpart[tt * 4 + (d >> 6)] = g;
        a0 = a1; a1 = a2; a2 = a3; a3 = cur;
    }
    cm[d] = sum * (1.f / 16.f);
    __syncthreads();
    if (d < 16) {
        float gg = gpart[d * 4 + 0] + gpart[d * 4 + 1] + gpart[d * 4 + 2] + gpart[d * 4 + 3];
        gate[(size_t)b * S_ + s0 + d] = 1.f / (1.f + expf(-(gg + bh[2])));
    }
    float accp = bp[d];
    const u16* wr = Wpt + (size_t)d * 256;
    #pragma unroll
    for (int k = 0; k < 256; k += 8) {
        bf16x8 w8 = *reinterpret_cast<const bf16x8*>(wr + k);
        accp += cm[k]     * (float)w8[0] + cm[k + 1] * (float)w8[1]
              + cm[k + 2] * (float)w8[2] + cm[k + 3] * (float)w8[3]
              + cm[k + 4] * (float)w8[4] + cm[k + 5] * (float)w8[5]
              + cm[k + 6] * (float)w8[6] + cm[k + 7] * (float)w8[7];
    }
    php[(size_t)blk * DS_ + d] = f2bf(accp);
}

// ---------------------------------------------------------------------------
// Packed launch, conv FIRST so its long-latency serial phase overlaps the
// qkv GEMM wavefront: blocks 0..511 conv+php; 512..2047 qkv GEMM (K=256).
// ---------------------------------------------------------------------------
__global__ __launch_bounds__(256) void step_a_k(
    const u16* __restrict__ h, const u16* __restrict__ Wqkvt,
    const float* __restrict__ bqkv, u16* __restrict__ qkv,
    const float* __restrict__ conv_w, const float* __restrict__ conv_b,
    const float* __restrict__ Wh, const float* __restrict__ bh,
    const u16* __restrict__ Wpt, const float* __restrict__ bp,
    u16* __restrict__ mixed, u16* __restrict__ php, float* __restrict__ gate)
{
    __shared__ __align__(16) unsigned char smem[65536];
    if (blockIdx.x < 512) {
        conv_dev(smem, blockIdx.x, h, conv_w, conv_b, Wh, bh,
                 Wpt, bp, mixed, php, gate);
    } else {
        mm256_dev<0>(smem, blockIdx.x - 512, 1536, 12, h, Wqkvt, bqkv, qkv,
                     768, nullptr, nullptr);
    }
}

// ---------------------------------------------------------------------------
// Banded scores via MFMA, single-stage (3 barriers total).
// ---------------------------------------------------------------------------
__global__ __launch_bounds__(256) void scores_k(
    const u16* __restrict__ qkv, float* __restrict__ scores)
{
    __shared__ __align__(16) unsigned char smem[65536];  // Q 16KB | K 48KB
    unsigned char* smQ = smem;
    unsigned char* smK = smem + 16384;
    float* Sld = reinterpret_cast<float*>(smem);         // [32][97], aliases Q

    const int bid = blockIdx.x;                    // 256 blocks
    const int blk = (bid & 7) * 32 + (bid >> 3);   // XCD swizzle (8 x 32)
    const int t0 = blk * 32;
    const int b  = t0 >> 11;
    const int s0 = t0 & (S_ - 1);
    const int tid = threadIdx.x;
    const int lane = tid & 63, wid = tid >> 6;
    const int lr = lane & 15, lc = lane >> 4;
    const int qt  = wid & 1;
    const int ktb = (wid >> 1) * 3;
    const int lrow2 = lane >> 5;
    const int g_lin = lane & 31;

    #pragma unroll
    for (int t = 0; t < 4; ++t) {
        int rbase = wid * 8 + t * 2;
        int row   = rbase + lrow2;
        int gg    = g_lin ^ (row & 15);
        GLD16(qkv + (size_t)(t0 + row) * 768 + gg * 8,
              smQ + (size_t)rbase * 512);
    }
    #pragma unroll
    for (int t = 0; t < 12; ++t) {
        int rbase = wid * 24 + t * 2;
        int row   = rbase + lrow2;
        int krow  = s0 - 64 + row; if (krow < 0) krow = 0;
        int gg    = g_lin ^ (row & 15);
        GLD16(qkv + ((size_t)(b * S_) + krow) * 768 + 256 + gg * 8,
              smK + (size_t)rbase * 512);
    }
    __syncthreads();

    f32x4 acc[3] = {};
    #pragma unroll
    for (int ks = 0; ks < 8; ++ks) {
        int m = qt * 16 + lr;
        bf16x8 af = *reinterpret_cast<const bf16x8*>(
            smQ + m * 512 + (((ks * 4 + lc) ^ (m & 15)) * 16));
        #pragma unroll
        for (int j = 0; j < 3; ++j) {
            int n = (ktb + j) * 16 + lr;
            bf16x8 bv = *reinterpret_cast<const bf16x8*>(
                smK + n * 512 + (((ks * 4 + lc) ^ (n & 15)) * 16));
            acc[j] = __builtin_amdgcn_mfma_f32_16x16x32_bf16(af, bv, acc[j], 0, 0, 0);
        }
    }
    __syncthreads();

    #pragma unroll
    for (int j = 0; j < 3; ++j) {
        int col = (ktb + j) * 16 + lr;
        #pragma unroll
        for (int r = 0; r < 4; ++r) {
            int row = qt * 16 + lc * 4 + r;
            Sld[row * 97 + col] = acc[j][r];
        }
    }
    __syncthreads();

    #pragma unroll
    for (int it = 0; it < 8; ++it) {
        int e = tid + it * 256;
        int i = e >> 6, l = e & 63;
        scores[(size_t)(t0 + i) * 64 + l] = Sld[i * 97 + i + l] * 0.0625f;
    }
}

// ---------------------------------------------------------------------------
// Top-8 select + softmax + V-sum. Top-8 via 64-lane bitonic sort
// (key = value desc, index asc -- identical order to jax.lax.top_k).
// ---------------------------------------------------------------------------
__global__ __launch_bounds__(256) void select_k(
    const float* __restrict__ scores, const u16* __restrict__ qkv,
    u16* __restrict__ summ)
{
    const int bid = blockIdx.x;                       // 2048 blocks
    const int sb  = (bid & 7) * 256 + (bid >> 3);     // bijective XCD swizzle
    const int m   = sb * 4 + (threadIdx.x >> 6);
    const int b = m >> 11;
    const int s = m & (S_ - 1);
    const int lane = threadIdx.x & 63;

    float v = (s - LB_ + lane >= 0) ? scores[(size_t)m * 64 + lane] : -INFINITY;
    int idx = lane;

    #pragma unroll
    for (int k = 2; k <= 64; k <<= 1) {
        #pragma unroll
        for (int j = k >> 1; j > 0; j >>= 1) {
            float ov = __shfl_xor(v, j);
            int   oi = __shfl_xor(idx, j);
            bool mineFirst = (v > ov) || (v == ov && idx < oi);
            bool lowLane  = (lane & j) == 0;
            bool dirFirst = (lane & k) == 0;
            bool keep = (lowLane == dirFirst) ? mineFirst : !mineFirst;
            if (!keep) { v = ov; idx = oi; }
        }
    }

    float vals[TOPK_]; int idxs[TOPK_];
    #pragma unroll
    for (int t = 0; t < TOPK_; ++t) {
        vals[t] = __shfl(v, t);
        idxs[t] = __shfl(idx, t);
    }

    const float mref = (vals[0] == -INFINITY) ? 0.f : vals[0];
    float e[TOPK_], ssum = 0.f;
    #pragma unroll
    for (int t = 0; t < TOPK_; ++t) { e[t] = expf(vals[t] - mref); ssum += e[t]; }
    const float inv = 1.f / fmaxf(ssum, 1e-30f);

    float o0 = 0.f, o1 = 0.f, o2 = 0.f, o3 = 0.f;
    #pragma unroll
    for (int t = 0; t < TOPK_; ++t) {
        float wt = e[t] * inv;
        int tok = s - LB_ + idxs[t];
        tok = min(max(tok, 0), S_ - 1);
        ushort4 vv = *reinterpret_cast<const ushort4*>(
            qkv + ((size_t)(b * S_) + tok) * 768 + 512 + lane * 4);
        o0 += wt * bf2f(vv.x);
        o1 += wt * bf2f(vv.y);
        o2 += wt * bf2f(vv.z);
        o3 += wt * bf2f(vv.w);
    }
    ushort4 pk;
    pk.x = f2bf(o0); pk.y = f2bf(o1); pk.z = f2bf(o2); pk.w = f2bf(o3);
    *reinterpret_cast<ushort4*>(summ + (size_t)m * DS_ + lane * 4) = pk;
}

// ---------------------------------------------------------------------------
// Merged prep: blocks 0..4095 cvt x->bf16; 4096..5183 weight transposes;
// 5184 qkv bias concat.
// ---------------------------------------------------------------------------
__global__ __launch_bounds__(256) void prep_all_k(
    const float* __restrict__ x,
    const float* __restrict__ Wi, const float* __restrict__ Wq,
    const float* __restrict__ Wk, const float* __restrict__ Wv,
    const float* __restrict__ Wp, const float* __restrict__ W1,
    const float* __restrict__ W2, const float* __restrict__ Wo,
    const float* __restrict__ bq, const float* __restrict__ bk,
    const float* __restrict__ bv,
    u16* __restrict__ xb,
    u16* __restrict__ Wit, u16* __restrict__ Wqkvt, u16* __restrict__ Wpt,
    u16* __restrict__ W1t, u16* __restrict__ W2t, u16* __restrict__ Wot,
    float* __restrict__ bqkv)
{
    const int bid0 = blockIdx.x;
    if (bid0 < 4096) {
        int i = (bid0 * 256 + threadIdx.x) * 8;
        float4 a = *reinterpret_cast<const float4*>(x + i);
        float4 b = *reinterpret_cast<const float4*>(x + i + 4);
        uint4 g;
        g.x = pack2(a.x, a.y); g.y = pack2(a.z, a.w);
        g.z = pack2(b.x, b.y); g.w = pack2(b.z, b.w);
        *reinterpret_cast<uint4*>(xb + i) = g;
        return;
    }
    const int bid = bid0 - 4096;
    if (bid >= 1088) {
        for (int i = threadIdx.x; i < 768; i += 256) {
            float v = (i < 256) ? bq[i] : (i < 512) ? bk[i - 256] : bv[i - 512];
            bqkv[i] = v;
        }
        return;
    }
    const float* in; u16* out; int K, N, t;
    if (bid < 256)      { in = Wi; out = Wit;             K = 1024; N = 256;  t = bid; }
    else if (bid < 320) { in = Wq; out = Wqkvt;           K = 256;  N = 256;  t = bid - 256; }
    else if (bid < 384) { in = Wk; out = Wqkvt + 256*256; K = 256;  N = 256;  t = bid - 320; }
    else if (bid < 448) { in = Wv; out = Wqkvt + 512*256; K = 256;  N = 256;  t = bid - 384; }
    else if (bid < 512) { in = Wp; out = Wpt;             K = 256;  N = 256;  t = bid - 448; }
    else if (bid < 768) { in = W1; out = W1t;             K = 1024; N = 256;  t = bid - 512; }
    else if (bid < 832) { in = W2; out = W2t;             K = 256;  N = 256;  t = bid - 768; }
    else                { in = Wo; out = Wot;             K = 256;  N = 1024; t = bid - 832; }
    const int tilesX = N >> 5;
    const int n0 = (t % tilesX) * 32, k0 = (t / tilesX) * 32;
    __shared__ float tl[32][33];
    const int cx = threadIdx.x & 31, cy = threadIdx.x >> 5;
    #pragma unroll
    for (int r = 0; r < 32; r += 8)
        tl[cy + r][cx] = in[(size_t)(k0 + cy + r) * N + n0 + cx];
    __syncthreads();
    #pragma unroll
    for (int r = 0; r < 32; r += 8)
        out[(size_t)(n0 + cy + r) * K + k0 + cx] = f2bf(tl[cx][cy + r]);
}

// ---------------------------------------------------------------------------
extern "C" void kernel_launch(void* const* d_in, const int* in_sizes, int n_in,
                              void* d_out, int out_size, void* d_ws, size_t ws_size,
                              hipStream_t stream)
{
    const float* x      = (const float*)d_in[0];
    const float* Wi     = (const float*)d_in[1];
    const float* bi     = (const float*)d_in[2];
    const float* conv_w = (const float*)d_in[3];
    const float* conv_b = (const float*)d_in[4];
    const float* Wp     = (const float*)d_in[5];
    const float* bp     = (const float*)d_in[6];
    const float* Wh     = (const float*)d_in[7];
    const float* bh     = (const float*)d_in[8];
    const float* Wq     = (const float*)d_in[9];
    const float* bq     = (const float*)d_in[10];
    const float* Wk     = (const float*)d_in[11];
    const float* bk     = (const float*)d_in[12];
    const float* Wv     = (const float*)d_in[13];
    const float* bv     = (const float*)d_in[14];
    const float* W1     = (const float*)d_in[15];
    const float* b1     = (const float*)d_in[16];
    const float* W2     = (const float*)d_in[17];
    const float* b2     = (const float*)d_in[18];
    const float* Wo     = (const float*)d_in[19];
    const float* bo     = (const float*)d_in[20];
    float* out = (float*)d_out;

    char* p = (char*)d_ws;
    auto alloc = [&](size_t bytes) { char* r = p; p += (bytes + 255) & ~(size_t)255; return r; };

    u16*  xb     = (u16*)alloc((size_t)BS_ * DM_ * 2);
    u16*  h      = (u16*)alloc((size_t)BS_ * DS_ * 2);
    u16*  mixed  = (u16*)alloc((size_t)BS_ * DS_ * 2);
    u16*  qkv    = (u16*)alloc((size_t)BS_ * 768 * 2);
    u16*  sm     = (u16*)alloc((size_t)BS_ * DS_ * 2);
    u16*  tb     = (u16*)alloc((size_t)BS_ * DS_ * 2);
    u16*  php    = (u16*)alloc((size_t)512 * DS_ * 2);
    float* gate  = (float*)alloc((size_t)BS_ * 4);
    float* scores= (float*)alloc((size_t)BS_ * 64 * 4);
    float* bqkv  = (float*)alloc(768 * 4);
    u16* Wit     = (u16*)alloc((size_t)256 * 1024 * 2);
    u16* Wqkvt   = (u16*)alloc((size_t)768 * 256 * 2);
    u16* Wpt     = (u16*)alloc((size_t)256 * 256 * 2);
    u16* W1t     = (u16*)alloc((size_t)256 * 1024 * 2);
    u16* W2t     = (u16*)alloc((size_t)256 * 256 * 2);
    u16* Wot     = (u16*)alloc((size_t)1024 * 256 * 2);

    dim3 blk(256);

    // ---- prep (cvt x + all weight transposes + bias concat) ----
    prep_all_k<<<5185, blk, 0, stream>>>(x, Wi, Wq, Wk, Wv, Wp, W1, W2, Wo,
                                         bq, bk, bv, xb,
                                         Wit, Wqkvt, Wpt, W1t, W2t, Wot, bqkv);

    // ---- forward ----
    // h = x @ Wi + bi   (K=1024 as 4 single-stage slabs)
    mm1024_k<0><<<512, blk, 0, stream>>>(xb, Wit, bi, h, DS_, 4, nullptr, nullptr);

    for (int step = 0; step < 2; ++step) {
        // packed: conv/pool/gate/php (512, first) + qkv GEMM (1536)
        step_a_k<<<2048, blk, 0, stream>>>(h, Wqkvt, bqkv, qkv,
                                           conv_w, conv_b, Wh, bh, Wpt, bp,
                                           mixed, php, gate);
        scores_k<<<256, blk, 0, stream>>>(qkv, scores);
        select_k<<<2048, blk, 0, stream>>>(scores, qkv, sm);
        mm_ui_k<<<512, blk, 0, stream>>>(h, mixed, php, sm, W1t, b1, tb);
        // h = h + (tanh(ui@W1+b1) @ W2 + b2) * gate   (K=256 single-stage)
        mm256_k<2><<<512, blk, 0, stream>>>(tb, W2t, b2, h, DS_, 4, h, gate);
    }

    // out = x + h @ Wo + bo   (K=256 single-stage)
    mm256_k<3><<<2048, blk, 0, stream>>>(h, Wot, bo, out, DM_, 16, xb, nullptr);
}

// Round 17
// 137.777 us; speedup vs baseline: 1.1689x; 1.0223x over previous
//
#include <hip/hip_runtime.h>
#include <math.h>

#define B_    4
#define S_    2048
#define BS_   8192       // B_*S_
#define DM_   1024
#define DS_   256
#define LB_   64
#define TOPK_ 8

typedef unsigned short u16;
typedef __bf16 bf16x8 __attribute__((ext_vector_type(8)));
typedef float  f32x4  __attribute__((ext_vector_type(4)));

static __device__ __forceinline__ u16 f2bf(float f) {
    union { float f; unsigned u; } a; a.f = f;
    unsigned u = a.u;
    unsigned r = u + 0x7FFFu + ((u >> 16) & 1u);   // RNE
    return (u16)(r >> 16);
}
static __device__ __forceinline__ float bf2f(u16 v) {
    union { unsigned u; float f; } a; a.u = ((unsigned)v) << 16; return a.f;
}
static __device__ __forceinline__ unsigned pack2(float a, float b) {
    return (unsigned)f2bf(a) | ((unsigned)f2bf(b) << 16);
}

// async global->LDS, 16B per lane; LDS dest = uniform base + lane*16
#define GLD16(g, l) __builtin_amdgcn_global_load_lds(                         \
    (const __attribute__((address_space(1))) void*)(g),                       \
    (__attribute__((address_space(3))) void*)(l), 16, 0, 0)

// ---------------------------------------------------------------------------
// Epilogue: EPI 0 -> C bf16 | 2 -> C bf16 = extra0_bf16 + val*extra1[m]
//           3 -> C f32 = extra0_bf16 + val.
// ---------------------------------------------------------------------------
template<int MF, int EPI>
__device__ __forceinline__ void epilogue(
    f32x4 (&acc)[MF][2], int bm, int bn, int wm, int wn, int lr, int lc,
    const float* __restrict__ bias, void* __restrict__ Cv, int N,
    const void* __restrict__ extra0v, const float* __restrict__ extra1)
{
    #pragma unroll
    for (int i = 0; i < MF; ++i) {
        #pragma unroll
        for (int j = 0; j < 2; ++j) {
            int col = bn + wn * 32 + j * 16 + lr;
            #pragma unroll
            for (int r = 0; r < 4; ++r) {
                int row = bm + wm * (MF * 16) + i * 16 + lc * 4 + r;
                float val = acc[i][j][r] + bias[col];
                if constexpr (EPI == 2) {
                    const u16* e0 = (const u16*)extra0v;
                    val = bf2f(e0[(size_t)row * N + col]) + val * extra1[row];
                    ((u16*)Cv)[(size_t)row * N + col] = f2bf(val);
                } else if constexpr (EPI == 3) {
                    const u16* e0 = (const u16*)extra0v;
                    ((float*)Cv)[(size_t)row * N + col] = bf2f(e0[(size_t)row * N + col]) + val;
                } else {
                    ((u16*)Cv)[(size_t)row * N + col] = f2bf(val);
                }
            }
        }
    }
}

// ---------------------------------------------------------------------------
// Shared compute: 32 MFMAs/wave over a staged 64x256 A-slab + 64x256 B-slab.
// LDS rows 512B (32 granules of 16B), granule swizzle g^(row&15).
// ---------------------------------------------------------------------------
__device__ __forceinline__ void slab_mfma(
    unsigned char* smA, unsigned char* smB, f32x4 (&acc)[2][2],
    int wm, int wn, int lr, int lc)
{
    #pragma unroll
    for (int kg = 0; kg < 8; ++kg) {
        bf16x8 af[2], bfr[2];
        #pragma unroll
        for (int i = 0; i < 2; ++i) {
            int m = wm * 32 + i * 16 + lr;
            af[i] = *reinterpret_cast<const bf16x8*>(
                smA + m * 512 + (((kg * 4 + lc) ^ (m & 15)) * 16));
        }
        #pragma unroll
        for (int j = 0; j < 2; ++j) {
            int n = wn * 32 + j * 16 + lr;
            bfr[j] = *reinterpret_cast<const bf16x8*>(
                smB + n * 512 + (((kg * 4 + lc) ^ (n & 15)) * 16));
        }
        #pragma unroll
        for (int i = 0; i < 2; ++i)
            #pragma unroll
            for (int j = 0; j < 2; ++j)
                acc[i][j] = __builtin_amdgcn_mfma_f32_16x16x32_bf16(
                    af[i], bfr[j], acc[i][j], 0, 0, 0);
    }
}

// ---------------------------------------------------------------------------
// Single-stage full-K GEMM for K=256: stage 64KB -> ONE barrier -> 32 MFMA.
// ---------------------------------------------------------------------------
template<int EPI>
__device__ __forceinline__ void mm256_dev(
    unsigned char* smem, int id, int nb, int gx,
    const u16* __restrict__ A, const u16* __restrict__ Bt,
    const float* __restrict__ bias, void* __restrict__ Cv,
    int N, const void* __restrict__ extra0v, const float* __restrict__ extra1)
{
    unsigned char* smA = smem;
    unsigned char* smB = smem + 32768;

    const int per = nb >> 3;
    const int nid = (id & 7) * per + (id >> 3);   // bijective XCD chunking
    const int bx  = nid % gx, by = nid / gx;

    const int lane = threadIdx.x & 63, wid = threadIdx.x >> 6;
    const int wm   = wid >> 1, wn = wid & 1;
    const int bm   = by * 64, bn = bx * 64;
    const int lr   = lane & 15, lc = lane >> 4;
    const int lrow2 = lane >> 5;        // row within 2-row gld op
    const int g_lin = lane & 31;        // granule slot within 512B row

    // stage A: 16 rows/wave, 2 rows per op -> 8 ops; same for B
    #pragma unroll
    for (int t = 0; t < 8; ++t) {
        int rbase = wid * 16 + t * 2;
        int row   = rbase + lrow2;
        int gg    = g_lin ^ (row & 15);
        GLD16(A + (size_t)(bm + row) * 256 + gg * 8, smA + (size_t)rbase * 512);
    }
    #pragma unroll
    for (int t = 0; t < 8; ++t) {
        int rbase = wid * 16 + t * 2;
        int row   = rbase + lrow2;
        int gg    = g_lin ^ (row & 15);
        GLD16(Bt + (size_t)(bn + row) * 256 + gg * 8, smB + (size_t)rbase * 512);
    }
    __syncthreads();

    f32x4 acc[2][2] = {};
    slab_mfma(smA, smB, acc, wm, wn, lr, lc);

    epilogue<2, EPI>(acc, bm, bn, wm, wn, lr, lc, bias, Cv, N, extra0v, extra1);
}

template<int EPI>
__global__ __launch_bounds__(256) void mm256_k(
    const u16* __restrict__ A, const u16* __restrict__ Bt,
    const float* __restrict__ bias, void* __restrict__ Cv,
    int N, int gx,
    const void* __restrict__ extra0v, const float* __restrict__ extra1)
{
    __shared__ __align__(16) unsigned char smem[65536];
    mm256_dev<EPI>(smem, blockIdx.x, gridDim.x, gx, A, Bt, bias, Cv, N,
                   extra0v, extra1);
}

// ---------------------------------------------------------------------------
// K=1024 GEMM as 4 sequential single-stage K=256 slabs (7 barriers total):
// for s: stage slab s (64KB) -> barrier -> 32 MFMA accumulate -> barrier.
// A pitch 1024 (xb), Bt pitch 1024. Used for Wi.
// ---------------------------------------------------------------------------
template<int EPI>
__global__ __launch_bounds__(256) void mm1024_k(
    const u16* __restrict__ A, const u16* __restrict__ Bt,
    const float* __restrict__ bias, void* __restrict__ Cv,
    int N, int gx,
    const void* __restrict__ extra0v, const float* __restrict__ extra1)
{
    __shared__ __align__(16) unsigned char smem[65536];
    unsigned char* smA = smem;
    unsigned char* smB = smem + 32768;

    const int nb  = gridDim.x;
    const int per = nb >> 3;
    const int id  = blockIdx.x;
    const int nid = (id & 7) * per + (id >> 3);
    const int bx  = nid % gx, by = nid / gx;

    const int lane = threadIdx.x & 63, wid = threadIdx.x >> 6;
    const int wm   = wid >> 1, wn = wid & 1;
    const int bm   = by * 64, bn = bx * 64;
    const int lr   = lane & 15, lc = lane >> 4;
    const int lrow2 = lane >> 5;
    const int g_lin = lane & 31;

    f32x4 acc[2][2] = {};

    #pragma unroll
    for (int s = 0; s < 4; ++s) {
        if (s) __syncthreads();   // previous slab's reads complete
        #pragma unroll
        for (int t = 0; t < 8; ++t) {
            int rbase = wid * 16 + t * 2;
            int row   = rbase + lrow2;
            int gg    = g_lin ^ (row & 15);
            GLD16(A + (size_t)(bm + row) * 1024 + s * 256 + gg * 8,
                  smA + (size_t)rbase * 512);
        }
        #pragma unroll
        for (int t = 0; t < 8; ++t) {
            int rbase = wid * 16 + t * 2;
            int row   = rbase + lrow2;
            int gg    = g_lin ^ (row & 15);
            GLD16(Bt + (size_t)(bn + row) * 1024 + s * 256 + gg * 8,
                  smB + (size_t)rbase * 512);
        }
        __syncthreads();
        slab_mfma(smA, smB, acc, wm, wn, lr, lc);
    }

    epilogue<2, EPI>(acc, bm, bn, wm, wn, lr, lc, bias, Cv, N, extra0v, extra1);
}

// ---------------------------------------------------------------------------
// ui-concat GEMM + tanh as 4 slabs; slab s's A-source = concat segment s
// (h | mixed | php(pool rows) | summ), each a full 256-col buffer.
// t = tanh([h|mixed|pb|summ] @ W1 + b1); pb[m,:] = php[m>>4,:].
// ---------------------------------------------------------------------------
__global__ __launch_bounds__(256) void mm_ui_k(
    const u16* __restrict__ h, const u16* __restrict__ mixed,
    const u16* __restrict__ php, const u16* __restrict__ summ,
    const u16* __restrict__ W1t, const float* __restrict__ b1,
    u16* __restrict__ t)
{
    __shared__ __align__(16) unsigned char smem[65536];
    unsigned char* smA = smem;
    unsigned char* smB = smem + 32768;

    const int nb  = gridDim.x;
    const int per = nb >> 3;
    const int id  = blockIdx.x;
    const int nid = (id & 7) * per + (id >> 3);
    const int bx  = nid & 3, by = nid >> 2;

    const int lane = threadIdx.x & 63, wid = threadIdx.x >> 6;
    const int wm   = wid >> 1, wn = wid & 1;
    const int bm   = by * 64, bn = bx * 64;
    const int lr   = lane & 15, lc = lane >> 4;
    const int lrow2 = lane >> 5;
    const int g_lin = lane & 31;

    f32x4 acc[2][2] = {};

    #pragma unroll
    for (int s = 0; s < 4; ++s) {
        const u16* Asrc = (s == 0) ? h : (s == 1) ? mixed : (s == 2) ? php : summ;
        if (s) __syncthreads();
        #pragma unroll
        for (int tt = 0; tt < 8; ++tt) {
            int rbase = wid * 16 + tt * 2;
            int row   = rbase + lrow2;
            int gg    = g_lin ^ (row & 15);
            int rs    = bm + row;
            if (s == 2) rs >>= 4;
            GLD16(Asrc + (size_t)rs * 256 + gg * 8, smA + (size_t)rbase * 512);
        }
        #pragma unroll
        for (int tt = 0; tt < 8; ++tt) {
            int rbase = wid * 16 + tt * 2;
            int row   = rbase + lrow2;
            int gg    = g_lin ^ (row & 15);
            GLD16(W1t + (size_t)(bn + row) * 1024 + s * 256 + gg * 8,
                  smB + (size_t)rbase * 512);
        }
        __syncthreads();
        slab_mfma(smA, smB, acc, wm, wn, lr, lc);
    }

    #pragma unroll
    for (int i = 0; i < 2; ++i) {
        #pragma unroll
        for (int j = 0; j < 2; ++j) {
            int col = bn + wn * 32 + j * 16 + lr;
            #pragma unroll
            for (int r = 0; r < 4; ++r) {
                int row = bm + wm * 32 + i * 16 + lc * 4 + r;
                t[(size_t)row * DS_ + col] = f2bf(tanhf(acc[i][j][r] + b1[col]));
            }
        }
    }
}

// ---------------------------------------------------------------------------
// Causal depthwise conv (K=5) + chunk mean + halt gate + fused php projection.
// ---------------------------------------------------------------------------
__device__ __forceinline__ void conv_dev(
    unsigned char* smem, int cid,
    const u16* __restrict__ h, const float* __restrict__ conv_w,
    const float* __restrict__ conv_b, const float* __restrict__ Wh,
    const float* __restrict__ bh, const u16* __restrict__ Wpt,
    const float* __restrict__ bp, u16* __restrict__ mixed,
    u16* __restrict__ php, float* __restrict__ gate)
{
    float* gpart = (float*)smem;            // [16][4]
    float* cm    = (float*)(smem + 256);    // [256]
    const int blk = (cid & 7) * 64 + (cid >> 3);   // XCD swizzle (8 x 64)
    const int d = threadIdx.x;
    const int b = blk >> 7;
    const int s0 = (blk & 127) * 16;
    const u16* hb = h + (size_t)b * S_ * DS_;
    u16* mb = mixed + (size_t)b * S_ * DS_;

    const float w0 = conv_w[0 * DS_ + d], w1 = conv_w[1 * DS_ + d],
                w2 = conv_w[2 * DS_ + d], w3 = conv_w[3 * DS_ + d],
                w4 = conv_w[4 * DS_ + d];
    const float cb = conv_b[d];
    const float whd = Wh[d * 3 + 2];

    float a0 = (s0 >= 4) ? bf2f(hb[(size_t)(s0 - 4) * DS_ + d]) : 0.f;
    float a1 = (s0 >= 3) ? bf2f(hb[(size_t)(s0 - 3) * DS_ + d]) : 0.f;
    float a2 = (s0 >= 2) ? bf2f(hb[(size_t)(s0 - 2) * DS_ + d]) : 0.f;
    float a3 = (s0 >= 1) ? bf2f(hb[(size_t)(s0 - 1) * DS_ + d]) : 0.f;

    float sum = 0.f;
    #pragma unroll
    for (int tt = 0; tt < 16; ++tt) {
        int s = s0 + tt;
        float cur = bf2f(hb[(size_t)s * DS_ + d]);
        mb[(size_t)s * DS_ + d] = f2bf(w0 * a0 + w1 * a1 + w2 * a2 + w3 * a3 + w4 * cur + cb);
        sum += cur;
        float g = cur * whd;
        #pragma unroll
        for (int off = 32; off; off >>= 1) g += __shfl_down(g, off);
        if ((d & 63) == 0) gpart[tt * 4 + (d >> 6)] = g;
        a0 = a1; a1 = a2; a2 = a3; a3 = cur;
    }
    cm[d] = sum * (1.f / 16.f);
    __syncthreads();
    if (d < 16) {
        float gg = gpart[d * 4 + 0] + gpart[d * 4 + 1] + gpart[d * 4 + 2] + gpart[d * 4 + 3];
        gate[(size_t)b * S_ + s0 + d] = 1.f / (1.f + expf(-(gg + bh[2])));
    }
    float accp = bp[d];
    const u16* wr = Wpt + (size_t)d * 256;
    #pragma unroll
    for (int k = 0; k < 256; k += 8) {
        bf16x8 w8 = *reinterpret_cast<const bf16x8*>(wr + k);
        accp += cm[k]     * (float)w8[0] + cm[k + 1] * (float)w8[1]
              + cm[k + 2] * (float)w8[2] + cm[k + 3] * (float)w8[3]
              + cm[k + 4] * (float)w8[4] + cm[k + 5] * (float)w8[5]
              + cm[k + 6] * (float)w8[6] + cm[k + 7] * (float)w8[7];
    }
    php[(size_t)blk * DS_ + d] = f2bf(accp);
}

// ---------------------------------------------------------------------------
// Packed launch: blocks 0..1535 qkv GEMM (single-stage K=256, N=768);
// 1536..2047 conv+php.   (R13 ordering -- measured best)
// ---------------------------------------------------------------------------
__global__ __launch_bounds__(256) void step_a_k(
    const u16* __restrict__ h, const u16* __restrict__ Wqkvt,
    const float* __restrict__ bqkv, u16* __restrict__ qkv,
    const float* __restrict__ conv_w, const float* __restrict__ conv_b,
    const float* __restrict__ Wh, const float* __restrict__ bh,
    const u16* __restrict__ Wpt, const float* __restrict__ bp,
    u16* __restrict__ mixed, u16* __restrict__ php, float* __restrict__ gate)
{
    __shared__ __align__(16) unsigned char smem[65536];
    if (blockIdx.x < 1536) {
        mm256_dev<0>(smem, blockIdx.x, 1536, 12, h, Wqkvt, bqkv, qkv,
                     768, nullptr, nullptr);
    } else {
        conv_dev(smem, blockIdx.x - 1536, h, conv_w, conv_b, Wh, bh,
                 Wpt, bp, mixed, php, gate);
    }
}

// ---------------------------------------------------------------------------
// Banded scores via MFMA, single-stage (3 barriers total).
// ---------------------------------------------------------------------------
__global__ __launch_bounds__(256) void scores_k(
    const u16* __restrict__ qkv, float* __restrict__ scores)
{
    __shared__ __align__(16) unsigned char smem[65536];  // Q 16KB | K 48KB
    unsigned char* smQ = smem;
    unsigned char* smK = smem + 16384;
    float* Sld = reinterpret_cast<float*>(smem);         // [32][97], aliases Q

    const int bid = blockIdx.x;                    // 256 blocks
    const int blk = (bid & 7) * 32 + (bid >> 3);   // XCD swizzle (8 x 32)
    const int t0 = blk * 32;
    const int b  = t0 >> 11;
    const int s0 = t0 & (S_ - 1);
    const int tid = threadIdx.x;
    const int lane = tid & 63, wid = tid >> 6;
    const int lr = lane & 15, lc = lane >> 4;
    const int qt  = wid & 1;
    const int ktb = (wid >> 1) * 3;
    const int lrow2 = lane >> 5;
    const int g_lin = lane & 31;

    #pragma unroll
    for (int t = 0; t < 4; ++t) {
        int rbase = wid * 8 + t * 2;
        int row   = rbase + lrow2;
        int gg    = g_lin ^ (row & 15);
        GLD16(qkv + (size_t)(t0 + row) * 768 + gg * 8,
              smQ + (size_t)rbase * 512);
    }
    #pragma unroll
    for (int t = 0; t < 12; ++t) {
        int rbase = wid * 24 + t * 2;
        int row   = rbase + lrow2;
        int krow  = s0 - 64 + row; if (krow < 0) krow = 0;
        int gg    = g_lin ^ (row & 15);
        GLD16(qkv + ((size_t)(b * S_) + krow) * 768 + 256 + gg * 8,
              smK + (size_t)rbase * 512);
    }
    __syncthreads();

    f32x4 acc[3] = {};
    #pragma unroll
    for (int ks = 0; ks < 8; ++ks) {
        int m = qt * 16 + lr;
        bf16x8 af = *reinterpret_cast<const bf16x8*>(
            smQ + m * 512 + (((ks * 4 + lc) ^ (m & 15)) * 16));
        #pragma unroll
        for (int j = 0; j < 3; ++j) {
            int n = (ktb + j) * 16 + lr;
            bf16x8 bv = *reinterpret_cast<const bf16x8*>(
                smK + n * 512 + (((ks * 4 + lc) ^ (n & 15)) * 16));
            acc[j] = __builtin_amdgcn_mfma_f32_16x16x32_bf16(af, bv, acc[j], 0, 0, 0);
        }
    }
    __syncthreads();

    #pragma unroll
    for (int j = 0; j < 3; ++j) {
        int col = (ktb + j) * 16 + lr;
        #pragma unroll
        for (int r = 0; r < 4; ++r) {
            int row = qt * 16 + lc * 4 + r;
            Sld[row * 97 + col] = acc[j][r];
        }
    }
    __syncthreads();

    #pragma unroll
    for (int it = 0; it < 8; ++it) {
        int e = tid + it * 256;
        int i = e >> 6, l = e & 63;
        scores[(size_t)(t0 + i) * 64 + l] = Sld[i * 97 + i + l] * 0.0625f;
    }
}

// ---------------------------------------------------------------------------
// Top-8 select + softmax + V-sum. Top-8 via 64-lane bitonic sort
// (key = value desc, index asc -- identical order to jax.lax.top_k).
// ---------------------------------------------------------------------------
__global__ __launch_bounds__(256) void select_k(
    const float* __restrict__ scores, const u16* __restrict__ qkv,
    u16* __restrict__ summ)
{
    const int bid = blockIdx.x;                       // 2048 blocks
    const int sb  = (bid & 7) * 256 + (bid >> 3);     // bijective XCD swizzle
    const int m   = sb * 4 + (threadIdx.x >> 6);
    const int b = m >> 11;
    const int s = m & (S_ - 1);
    const int lane = threadIdx.x & 63;

    float v = (s - LB_ + lane >= 0) ? scores[(size_t)m * 64 + lane] : -INFINITY;
    int idx = lane;

    #pragma unroll
    for (int k = 2; k <= 64; k <<= 1) {
        #pragma unroll
        for (int j = k >> 1; j > 0; j >>= 1) {
            float ov = __shfl_xor(v, j);
            int   oi = __shfl_xor(idx, j);
            bool mineFirst = (v > ov) || (v == ov && idx < oi);
            bool lowLane  = (lane & j) == 0;
            bool dirFirst = (lane & k) == 0;
            bool keep = (lowLane == dirFirst) ? mineFirst : !mineFirst;
            if (!keep) { v = ov; idx = oi; }
        }
    }

    float vals[TOPK_]; int idxs[TOPK_];
    #pragma unroll
    for (int t = 0; t < TOPK_; ++t) {
        vals[t] = __shfl(v, t);
        idxs[t] = __shfl(idx, t);
    }

    const float mref = (vals[0] == -INFINITY) ? 0.f : vals[0];
    float e[TOPK_], ssum = 0.f;
    #pragma unroll
    for (int t = 0; t < TOPK_; ++t) { e[t] = expf(vals[t] - mref); ssum += e[t]; }
    const float inv = 1.f / fmaxf(ssum, 1e-30f);

    float o0 = 0.f, o1 = 0.f, o2 = 0.f, o3 = 0.f;
    #pragma unroll
    for (int t = 0; t < TOPK_; ++t) {
        float wt = e[t] * inv;
        int tok = s - LB_ + idxs[t];
        tok = min(max(tok, 0), S_ - 1);
        ushort4 vv = *reinterpret_cast<const ushort4*>(
            qkv + ((size_t)(b * S_) + tok) * 768 + 512 + lane * 4);
        o0 += wt * bf2f(vv.x);
        o1 += wt * bf2f(vv.y);
        o2 += wt * bf2f(vv.z);
        o3 += wt * bf2f(vv.w);
    }
    ushort4 pk;
    pk.x = f2bf(o0); pk.y = f2bf(o1); pk.z = f2bf(o2); pk.w = f2bf(o3);
    *reinterpret_cast<ushort4*>(summ + (size_t)m * DS_ + lane * 4) = pk;
}

// ---------------------------------------------------------------------------
// Merged prep: blocks 0..4095 cvt x->bf16; 4096..5183 weight transposes;
// 5184 qkv bias concat.
// ---------------------------------------------------------------------------
__global__ __launch_bounds__(256) void prep_all_k(
    const float* __restrict__ x,
    const float* __restrict__ Wi, const float* __restrict__ Wq,
    const float* __restrict__ Wk, const float* __restrict__ Wv,
    const float* __restrict__ Wp, const float* __restrict__ W1,
    const float* __restrict__ W2, const float* __restrict__ Wo,
    const float* __restrict__ bq, const float* __restrict__ bk,
    const float* __restrict__ bv,
    u16* __restrict__ xb,
    u16* __restrict__ Wit, u16* __restrict__ Wqkvt, u16* __restrict__ Wpt,
    u16* __restrict__ W1t, u16* __restrict__ W2t, u16* __restrict__ Wot,
    float* __restrict__ bqkv)
{
    const int bid0 = blockIdx.x;
    if (bid0 < 4096) {
        int i = (bid0 * 256 + threadIdx.x) * 8;
        float4 a = *reinterpret_cast<const float4*>(x + i);
        float4 b = *reinterpret_cast<const float4*>(x + i + 4);
        uint4 g;
        g.x = pack2(a.x, a.y); g.y = pack2(a.z, a.w);
        g.z = pack2(b.x, b.y); g.w = pack2(b.z, b.w);
        *reinterpret_cast<uint4*>(xb + i) = g;
        return;
    }
    const int bid = bid0 - 4096;
    if (bid >= 1088) {
        for (int i = threadIdx.x; i < 768; i += 256) {
            float v = (i < 256) ? bq[i] : (i < 512) ? bk[i - 256] : bv[i - 512];
            bqkv[i] = v;
        }
        return;
    }
    const float* in; u16* out; int K, N, t;
    if (bid < 256)      { in = Wi; out = Wit;             K = 1024; N = 256;  t = bid; }
    else if (bid < 320) { in = Wq; out = Wqkvt;           K = 256;  N = 256;  t = bid - 256; }
    else if (bid < 384) { in = Wk; out = Wqkvt + 256*256; K = 256;  N = 256;  t = bid - 320; }
    else if (bid < 448) { in = Wv; out = Wqkvt + 512*256; K = 256;  N = 256;  t = bid - 384; }
    else if (bid < 512) { in = Wp; out = Wpt;             K = 256;  N = 256;  t = bid - 448; }
    else if (bid < 768) { in = W1; out = W1t;             K = 1024; N = 256;  t = bid - 512; }
    else if (bid < 832) { in = W2; out = W2t;             K = 256;  N = 256;  t = bid - 768; }
    else                { in = Wo; out = Wot;             K = 256;  N = 1024; t = bid - 832; }
    const int tilesX = N >> 5;
    const int n0 = (t % tilesX) * 32, k0 = (t / tilesX) * 32;
    __shared__ float tl[32][33];
    const int cx = threadIdx.x & 31, cy = threadIdx.x >> 5;
    #pragma unroll
    for (int r = 0; r < 32; r += 8)
        tl[cy + r][cx] = in[(size_t)(k0 + cy + r) * N + n0 + cx];
    __syncthreads();
    #pragma unroll
    for (int r = 0; r < 32; r += 8)
        out[(size_t)(n0 + cy + r) * K + k0 + cx] = f2bf(tl[cx][cy + r]);
}

// ---------------------------------------------------------------------------
extern "C" void kernel_launch(void* const* d_in, const int* in_sizes, int n_in,
                              void* d_out, int out_size, void* d_ws, size_t ws_size,
                              hipStream_t stream)
{
    const float* x      = (const float*)d_in[0];
    const float* Wi     = (const float*)d_in[1];
    const float* bi     = (const float*)d_in[2];
    const float* conv_w = (const float*)d_in[3];
    const float* conv_b = (const float*)d_in[4];
    const float* Wp     = (const float*)d_in[5];
    const float* bp     = (const float*)d_in[6];
    const float* Wh     = (const float*)d_in[7];
    const float* bh     = (const float*)d_in[8];
    const float* Wq     = (const float*)d_in[9];
    const float* bq     = (const float*)d_in[10];
    const float* Wk     = (const float*)d_in[11];
    const float* bk     = (const float*)d_in[12];
    const float* Wv     = (const float*)d_in[13];
    const float* bv     = (const float*)d_in[14];
    const float* W1     = (const float*)d_in[15];
    const float* b1     = (const float*)d_in[16];
    const float* W2     = (const float*)d_in[17];
    const float* b2     = (const float*)d_in[18];
    const float* Wo     = (const float*)d_in[19];
    const float* bo     = (const float*)d_in[20];
    float* out = (float*)d_out;

    char* p = (char*)d_ws;
    auto alloc = [&](size_t bytes) { char* r = p; p += (bytes + 255) & ~(size_t)255; return r; };

    u16*  xb     = (u16*)alloc((size_t)BS_ * DM_ * 2);
    u16*  h      = (u16*)alloc((size_t)BS_ * DS_ * 2);
    u16*  mixed  = (u16*)alloc((size_t)BS_ * DS_ * 2);
    u16*  qkv    = (u16*)alloc((size_t)BS_ * 768 * 2);
    u16*  sm     = (u16*)alloc((size_t)BS_ * DS_ * 2);
    u16*  tb     = (u16*)alloc((size_t)BS_ * DS_ * 2);
    u16*  php    = (u16*)alloc((size_t)512 * DS_ * 2);
    float* gate  = (float*)alloc((size_t)BS_ * 4);
    float* scores= (float*)alloc((size_t)BS_ * 64 * 4);
    float* bqkv  = (float*)alloc(768 * 4);
    u16* Wit     = (u16*)alloc((size_t)256 * 1024 * 2);
    u16* Wqkvt   = (u16*)alloc((size_t)768 * 256 * 2);
    u16* Wpt     = (u16*)alloc((size_t)256 * 256 * 2);
    u16* W1t     = (u16*)alloc((size_t)256 * 1024 * 2);
    u16* W2t     = (u16*)alloc((size_t)256 * 256 * 2);
    u16* Wot     = (u16*)alloc((size_t)1024 * 256 * 2);

    dim3 blk(256);

    // ---- prep (cvt x + all weight transposes + bias concat) ----
    prep_all_k<<<5185, blk, 0, stream>>>(x, Wi, Wq, Wk, Wv, Wp, W1, W2, Wo,
                                         bq, bk, bv, xb,
                                         Wit, Wqkvt, Wpt, W1t, W2t, Wot, bqkv);

    // ---- forward ----
    // h = x @ Wi + bi   (K=1024 as 4 single-stage slabs)
    mm1024_k<0><<<512, blk, 0, stream>>>(xb, Wit, bi, h, DS_, 4, nullptr, nullptr);

    for (int step = 0; step < 2; ++step) {
        // packed: qkv single-stage GEMM (1536) + conv/pool/gate/php (512)
        step_a_k<<<2048, blk, 0, stream>>>(h, Wqkvt, bqkv, qkv,
                                           conv_w, conv_b, Wh, bh, Wpt, bp,
                                           mixed, php, gate);
        scores_k<<<256, blk, 0, stream>>>(qkv, scores);
        select_k<<<2048, blk, 0, stream>>>(scores, qkv, sm);
        mm_ui_k<<<512, blk, 0, stream>>>(h, mixed, php, sm, W1t, b1, tb);
        // h = h + (tanh(ui@W1+b1) @ W2 + b2) * gate   (K=256 single-stage)
        mm256_k<2><<<512, blk, 0, stream>>>(tb, W2t, b2, h, DS_, 4, h, gate);
    }

    // out = x + h @ Wo + bo   (K=256 single-stage)
    mm256_k<3><<<2048, blk, 0, stream>>>(h, Wot, bo, out, DM_, 16, xb, nullptr);
}

// Round 18
// 137.367 us; speedup vs baseline: 1.1724x; 1.0030x over previous
//
#include <hip/hip_runtime.h>
#include <math.h>

#define B_    4
#define S_    2048
#define BS_   8192       // B_*S_
#define DM_   1024
#define DS_   256
#define LB_   64
#define TOPK_ 8

typedef unsigned short u16;
typedef __bf16 bf16x8 __attribute__((ext_vector_type(8)));
typedef float  f32x4  __attribute__((ext_vector_type(4)));

static __device__ __forceinline__ u16 f2bf(float f) {
    union { float f; unsigned u; } a; a.f = f;
    unsigned u = a.u;
    unsigned r = u + 0x7FFFu + ((u >> 16) & 1u);   // RNE
    return (u16)(r >> 16);
}
static __device__ __forceinline__ float bf2f(u16 v) {
    union { unsigned u; float f; } a; a.u = ((unsigned)v) << 16; return a.f;
}
static __device__ __forceinline__ unsigned pack2(float a, float b) {
    return (unsigned)f2bf(a) | ((unsigned)f2bf(b) << 16);
}

// async global->LDS, 16B per lane; LDS dest = uniform base + lane*16
#define GLD16(g, l) __builtin_amdgcn_global_load_lds(                         \
    (const __attribute__((address_space(1))) void*)(g),                       \
    (__attribute__((address_space(3))) void*)(l), 16, 0, 0)

// ---------------------------------------------------------------------------
// Epilogue: EPI 0 -> C bf16 | 2 -> C bf16 = extra0_bf16 + val*extra1[m]
//           3 -> C f32 = extra0_bf16 + val.
// ---------------------------------------------------------------------------
template<int MF, int EPI>
__device__ __forceinline__ void epilogue(
    f32x4 (&acc)[MF][2], int bm, int bn, int wm, int wn, int lr, int lc,
    const float* __restrict__ bias, void* __restrict__ Cv, int N,
    const void* __restrict__ extra0v, const float* __restrict__ extra1)
{
    #pragma unroll
    for (int i = 0; i < MF; ++i) {
        #pragma unroll
        for (int j = 0; j < 2; ++j) {
            int col = bn + wn * 32 + j * 16 + lr;
            #pragma unroll
            for (int r = 0; r < 4; ++r) {
                int row = bm + wm * (MF * 16) + i * 16 + lc * 4 + r;
                float val = acc[i][j][r] + bias[col];
                if constexpr (EPI == 2) {
                    const u16* e0 = (const u16*)extra0v;
                    val = bf2f(e0[(size_t)row * N + col]) + val * extra1[row];
                    ((u16*)Cv)[(size_t)row * N + col] = f2bf(val);
                } else if constexpr (EPI == 3) {
                    const u16* e0 = (const u16*)extra0v;
                    ((float*)Cv)[(size_t)row * N + col] = bf2f(e0[(size_t)row * N + col]) + val;
                } else {
                    ((u16*)Cv)[(size_t)row * N + col] = f2bf(val);
                }
            }
        }
    }
}

// ---------------------------------------------------------------------------
// Shared compute over a staged 64x256 A-slab + 64x256 B-slab, with SPLIT
// accumulators: even kg -> acc, odd kg -> acc2. Halves the MFMA dependency
// chain depth (8 independent chains/wave instead of 4). Caller merges
// acc += acc2 before the epilogue.
// LDS rows 512B (32 granules of 16B), granule swizzle g^(row&15).
// ---------------------------------------------------------------------------
__device__ __forceinline__ void slab_mfma(
    unsigned char* smA, unsigned char* smB,
    f32x4 (&acc)[2][2], f32x4 (&acc2)[2][2],
    int wm, int wn, int lr, int lc)
{
    #pragma unroll
    for (int kg = 0; kg < 8; kg += 2) {
        bf16x8 af0[2], bf0[2], af1[2], bf1[2];
        #pragma unroll
        for (int i = 0; i < 2; ++i) {
            int m = wm * 32 + i * 16 + lr;
            af0[i] = *reinterpret_cast<const bf16x8*>(
                smA + m * 512 + ((((kg + 0) * 4 + lc) ^ (m & 15)) * 16));
            af1[i] = *reinterpret_cast<const bf16x8*>(
                smA + m * 512 + ((((kg + 1) * 4 + lc) ^ (m & 15)) * 16));
        }
        #pragma unroll
        for (int j = 0; j < 2; ++j) {
            int n = wn * 32 + j * 16 + lr;
            bf0[j] = *reinterpret_cast<const bf16x8*>(
                smB + n * 512 + ((((kg + 0) * 4 + lc) ^ (n & 15)) * 16));
            bf1[j] = *reinterpret_cast<const bf16x8*>(
                smB + n * 512 + ((((kg + 1) * 4 + lc) ^ (n & 15)) * 16));
        }
        #pragma unroll
        for (int i = 0; i < 2; ++i)
            #pragma unroll
            for (int j = 0; j < 2; ++j) {
                acc[i][j]  = __builtin_amdgcn_mfma_f32_16x16x32_bf16(
                    af0[i], bf0[j], acc[i][j], 0, 0, 0);
                acc2[i][j] = __builtin_amdgcn_mfma_f32_16x16x32_bf16(
                    af1[i], bf1[j], acc2[i][j], 0, 0, 0);
            }
    }
}

// ---------------------------------------------------------------------------
// Single-stage full-K GEMM for K=256: stage 64KB -> ONE barrier -> 32 MFMA.
// ---------------------------------------------------------------------------
template<int EPI>
__device__ __forceinline__ void mm256_dev(
    unsigned char* smem, int id, int nb, int gx,
    const u16* __restrict__ A, const u16* __restrict__ Bt,
    const float* __restrict__ bias, void* __restrict__ Cv,
    int N, const void* __restrict__ extra0v, const float* __restrict__ extra1)
{
    unsigned char* smA = smem;
    unsigned char* smB = smem + 32768;

    const int per = nb >> 3;
    const int nid = (id & 7) * per + (id >> 3);   // bijective XCD chunking
    const int bx  = nid % gx, by = nid / gx;

    const int lane = threadIdx.x & 63, wid = threadIdx.x >> 6;
    const int wm   = wid >> 1, wn = wid & 1;
    const int bm   = by * 64, bn = bx * 64;
    const int lr   = lane & 15, lc = lane >> 4;
    const int lrow2 = lane >> 5;        // row within 2-row gld op
    const int g_lin = lane & 31;        // granule slot within 512B row

    #pragma unroll
    for (int t = 0; t < 8; ++t) {
        int rbase = wid * 16 + t * 2;
        int row   = rbase + lrow2;
        int gg    = g_lin ^ (row & 15);
        GLD16(A + (size_t)(bm + row) * 256 + gg * 8, smA + (size_t)rbase * 512);
    }
    #pragma unroll
    for (int t = 0; t < 8; ++t) {
        int rbase = wid * 16 + t * 2;
        int row   = rbase + lrow2;
        int gg    = g_lin ^ (row & 15);
        GLD16(Bt + (size_t)(bn + row) * 256 + gg * 8, smB + (size_t)rbase * 512);
    }
    __syncthreads();

    f32x4 acc[2][2] = {}, acc2[2][2] = {};
    slab_mfma(smA, smB, acc, acc2, wm, wn, lr, lc);
    #pragma unroll
    for (int i = 0; i < 2; ++i)
        #pragma unroll
        for (int j = 0; j < 2; ++j)
            acc[i][j] += acc2[i][j];

    epilogue<2, EPI>(acc, bm, bn, wm, wn, lr, lc, bias, Cv, N, extra0v, extra1);
}

template<int EPI>
__global__ __launch_bounds__(256) void mm256_k(
    const u16* __restrict__ A, const u16* __restrict__ Bt,
    const float* __restrict__ bias, void* __restrict__ Cv,
    int N, int gx,
    const void* __restrict__ extra0v, const float* __restrict__ extra1)
{
    __shared__ __align__(16) unsigned char smem[65536];
    mm256_dev<EPI>(smem, blockIdx.x, gridDim.x, gx, A, Bt, bias, Cv, N,
                   extra0v, extra1);
}

// ---------------------------------------------------------------------------
// K=1024 GEMM as 4 sequential single-stage K=256 slabs (7 barriers total).
// A pitch 1024 (xb), Bt pitch 1024. Used for Wi.
// ---------------------------------------------------------------------------
template<int EPI>
__global__ __launch_bounds__(256) void mm1024_k(
    const u16* __restrict__ A, const u16* __restrict__ Bt,
    const float* __restrict__ bias, void* __restrict__ Cv,
    int N, int gx,
    const void* __restrict__ extra0v, const float* __restrict__ extra1)
{
    __shared__ __align__(16) unsigned char smem[65536];
    unsigned char* smA = smem;
    unsigned char* smB = smem + 32768;

    const int nb  = gridDim.x;
    const int per = nb >> 3;
    const int id  = blockIdx.x;
    const int nid = (id & 7) * per + (id >> 3);
    const int bx  = nid % gx, by = nid / gx;

    const int lane = threadIdx.x & 63, wid = threadIdx.x >> 6;
    const int wm   = wid >> 1, wn = wid & 1;
    const int bm   = by * 64, bn = bx * 64;
    const int lr   = lane & 15, lc = lane >> 4;
    const int lrow2 = lane >> 5;
    const int g_lin = lane & 31;

    f32x4 acc[2][2] = {}, acc2[2][2] = {};

    #pragma unroll
    for (int s = 0; s < 4; ++s) {
        if (s) __syncthreads();   // previous slab's reads complete
        #pragma unroll
        for (int t = 0; t < 8; ++t) {
            int rbase = wid * 16 + t * 2;
            int row   = rbase + lrow2;
            int gg    = g_lin ^ (row & 15);
            GLD16(A + (size_t)(bm + row) * 1024 + s * 256 + gg * 8,
                  smA + (size_t)rbase * 512);
        }
        #pragma unroll
        for (int t = 0; t < 8; ++t) {
            int rbase = wid * 16 + t * 2;
            int row   = rbase + lrow2;
            int gg    = g_lin ^ (row & 15);
            GLD16(Bt + (size_t)(bn + row) * 1024 + s * 256 + gg * 8,
                  smB + (size_t)rbase * 512);
        }
        __syncthreads();
        slab_mfma(smA, smB, acc, acc2, wm, wn, lr, lc);
    }
    #pragma unroll
    for (int i = 0; i < 2; ++i)
        #pragma unroll
        for (int j = 0; j < 2; ++j)
            acc[i][j] += acc2[i][j];

    epilogue<2, EPI>(acc, bm, bn, wm, wn, lr, lc, bias, Cv, N, extra0v, extra1);
}

// ---------------------------------------------------------------------------
// ui-concat GEMM + tanh as 4 slabs; slab s's A-source = concat segment s
// (h | mixed | php(pool rows) | summ), each a full 256-col buffer.
// t = tanh([h|mixed|pb|summ] @ W1 + b1); pb[m,:] = php[m>>4,:].
// ---------------------------------------------------------------------------
__global__ __launch_bounds__(256) void mm_ui_k(
    const u16* __restrict__ h, const u16* __restrict__ mixed,
    const u16* __restrict__ php, const u16* __restrict__ summ,
    const u16* __restrict__ W1t, const float* __restrict__ b1,
    u16* __restrict__ t)
{
    __shared__ __align__(16) unsigned char smem[65536];
    unsigned char* smA = smem;
    unsigned char* smB = smem + 32768;

    const int nb  = gridDim.x;
    const int per = nb >> 3;
    const int id  = blockIdx.x;
    const int nid = (id & 7) * per + (id >> 3);
    const int bx  = nid & 3, by = nid >> 2;

    const int lane = threadIdx.x & 63, wid = threadIdx.x >> 6;
    const int wm   = wid >> 1, wn = wid & 1;
    const int bm   = by * 64, bn = bx * 64;
    const int lr   = lane & 15, lc = lane >> 4;
    const int lrow2 = lane >> 5;
    const int g_lin = lane & 31;

    f32x4 acc[2][2] = {}, acc2[2][2] = {};

    #pragma unroll
    for (int s = 0; s < 4; ++s) {
        const u16* Asrc = (s == 0) ? h : (s == 1) ? mixed : (s == 2) ? php : summ;
        if (s) __syncthreads();
        #pragma unroll
        for (int tt = 0; tt < 8; ++tt) {
            int rbase = wid * 16 + tt * 2;
            int row   = rbase + lrow2;
            int gg    = g_lin ^ (row & 15);
            int rs    = bm + row;
            if (s == 2) rs >>= 4;
            GLD16(Asrc + (size_t)rs * 256 + gg * 8, smA + (size_t)rbase * 512);
        }
        #pragma unroll
        for (int tt = 0; tt < 8; ++tt) {
            int rbase = wid * 16 + tt * 2;
            int row   = rbase + lrow2;
            int gg    = g_lin ^ (row & 15);
            GLD16(W1t + (size_t)(bn + row) * 1024 + s * 256 + gg * 8,
                  smB + (size_t)rbase * 512);
        }
        __syncthreads();
        slab_mfma(smA, smB, acc, acc2, wm, wn, lr, lc);
    }

    #pragma unroll
    for (int i = 0; i < 2; ++i) {
        #pragma unroll
        for (int j = 0; j < 2; ++j) {
            int col = bn + wn * 32 + j * 16 + lr;
            #pragma unroll
            for (int r = 0; r < 4; ++r) {
                int row = bm + wm * 32 + i * 16 + lc * 4 + r;
                float v = acc[i][j][r] + acc2[i][j][r];
                t[(size_t)row * DS_ + col] = f2bf(tanhf(v + b1[col]));
            }
        }
    }
}

// ---------------------------------------------------------------------------
// Causal depthwise conv (K=5) + chunk mean + halt gate + fused php projection.
// ---------------------------------------------------------------------------
__device__ __forceinline__ void conv_dev(
    unsigned char* smem, int cid,
    const u16* __restrict__ h, const float* __restrict__ conv_w,
    const float* __restrict__ conv_b, const float* __restrict__ Wh,
    const float* __restrict__ bh, const u16* __restrict__ Wpt,
    const float* __restrict__ bp, u16* __restrict__ mixed,
    u16* __restrict__ php, float* __restrict__ gate)
{
    float* gpart = (float*)smem;            // [16][4]
    float* cm    = (float*)(smem + 256);    // [256]
    const int blk = (cid & 7) * 64 + (cid >> 3);   // XCD swizzle (8 x 64)
    const int d = threadIdx.x;
    const int b = blk >> 7;
    const int s0 = (blk & 127) * 16;
    const u16* hb = h + (size_t)b * S_ * DS_;
    u16* mb = mixed + (size_t)b * S_ * DS_;

    const float w0 = conv_w[0 * DS_ + d], w1 = conv_w[1 * DS_ + d],
                w2 = conv_w[2 * DS_ + d], w3 = conv_w[3 * DS_ + d],
                w4 = conv_w[4 * DS_ + d];
    const float cb = conv_b[d];
    const float whd = Wh[d * 3 + 2];

    float a0 = (s0 >= 4) ? bf2f(hb[(size_t)(s0 - 4) * DS_ + d]) : 0.f;
    float a1 = (s0 >= 3) ? bf2f(hb[(size_t)(s0 - 3) * DS_ + d]) : 0.f;
    float a2 = (s0 >= 2) ? bf2f(hb[(size_t)(s0 - 2) * DS_ + d]) : 0.f;
    float a3 = (s0 >= 1) ? bf2f(hb[(size_t)(s0 - 1) * DS_ + d]) : 0.f;

    float sum = 0.f;
    #pragma unroll
    for (int tt = 0; tt < 16; ++tt) {
        int s = s0 + tt;
        float cur = bf2f(hb[(size_t)s * DS_ + d]);
        mb[(size_t)s * DS_ + d] = f2bf(w0 * a0 + w1 * a1 + w2 * a2 + w3 * a3 + w4 * cur + cb);
        sum += cur;
        float g = cur * whd;
        #pragma unroll
        for (int off = 32; off; off >>= 1) g += __shfl_down(g, off);
        if ((d & 63) == 0) gpart[tt * 4 + (d >> 6)] = g;
        a0 = a1; a1 = a2; a2 = a3; a3 = cur;
    }
    cm[d] = sum * (1.f / 16.f);
    __syncthreads();
    if (d < 16) {
        float gg = gpart[d * 4 + 0] + gpart[d * 4 + 1] + gpart[d * 4 + 2] + gpart[d * 4 + 3];
        gate[(size_t)b * S_ + s0 + d] = 1.f / (1.f + expf(-(gg + bh[2])));
    }
    float accp = bp[d];
    const u16* wr = Wpt + (size_t)d * 256;
    #pragma unroll
    for (int k = 0; k < 256; k += 8) {
        bf16x8 w8 = *reinterpret_cast<const bf16x8*>(wr + k);
        accp += cm[k]     * (float)w8[0] + cm[k + 1] * (float)w8[1]
              + cm[k + 2] * (float)w8[2] + cm[k + 3] * (float)w8[3]
              + cm[k + 4] * (float)w8[4] + cm[k + 5] * (float)w8[5]
              + cm[k + 6] * (float)w8[6] + cm[k + 7] * (float)w8[7];
    }
    php[(size_t)blk * DS_ + d] = f2bf(accp);
}

// ---------------------------------------------------------------------------
// Packed launch: blocks 0..1535 qkv GEMM (single-stage K=256, N=768);
// 1536..2047 conv+php.   (R13 ordering -- measured best)
// ---------------------------------------------------------------------------
__global__ __launch_bounds__(256) void step_a_k(
    const u16* __restrict__ h, const u16* __restrict__ Wqkvt,
    const float* __restrict__ bqkv, u16* __restrict__ qkv,
    const float* __restrict__ conv_w, const float* __restrict__ conv_b,
    const float* __restrict__ Wh, const float* __restrict__ bh,
    const u16* __restrict__ Wpt, const float* __restrict__ bp,
    u16* __restrict__ mixed, u16* __restrict__ php, float* __restrict__ gate)
{
    __shared__ __align__(16) unsigned char smem[65536];
    if (blockIdx.x < 1536) {
        mm256_dev<0>(smem, blockIdx.x, 1536, 12, h, Wqkvt, bqkv, qkv,
                     768, nullptr, nullptr);
    } else {
        conv_dev(smem, blockIdx.x - 1536, h, conv_w, conv_b, Wh, bh,
                 Wpt, bp, mixed, php, gate);
    }
}

// ---------------------------------------------------------------------------
// Banded scores via MFMA, single-stage (3 barriers total), split accumulators
// (6 independent MFMA chains/wave instead of 3).
// ---------------------------------------------------------------------------
__global__ __launch_bounds__(256) void scores_k(
    const u16* __restrict__ qkv, float* __restrict__ scores)
{
    __shared__ __align__(16) unsigned char smem[65536];  // Q 16KB | K 48KB
    unsigned char* smQ = smem;
    unsigned char* smK = smem + 16384;
    float* Sld = reinterpret_cast<float*>(smem);         // [32][97], aliases Q

    const int bid = blockIdx.x;                    // 256 blocks
    const int blk = (bid & 7) * 32 + (bid >> 3);   // XCD swizzle (8 x 32)
    const int t0 = blk * 32;
    const int b  = t0 >> 11;
    const int s0 = t0 & (S_ - 1);
    const int tid = threadIdx.x;
    const int lane = tid & 63, wid = tid >> 6;
    const int lr = lane & 15, lc = lane >> 4;
    const int qt  = wid & 1;
    const int ktb = (wid >> 1) * 3;
    const int lrow2 = lane >> 5;
    const int g_lin = lane & 31;

    #pragma unroll
    for (int t = 0; t < 4; ++t) {
        int rbase = wid * 8 + t * 2;
        int row   = rbase + lrow2;
        int gg    = g_lin ^ (row & 15);
        GLD16(qkv + (size_t)(t0 + row) * 768 + gg * 8,
              smQ + (size_t)rbase * 512);
    }
    #pragma unroll
    for (int t = 0; t < 12; ++t) {
        int rbase = wid * 24 + t * 2;
        int row   = rbase + lrow2;
        int krow  = s0 - 64 + row; if (krow < 0) krow = 0;
        int gg    = g_lin ^ (row & 15);
        GLD16(qkv + ((size_t)(b * S_) + krow) * 768 + 256 + gg * 8,
              smK + (size_t)rbase * 512);
    }
    __syncthreads();

    f32x4 acc[3] = {}, acc2[3] = {};
    #pragma unroll
    for (int ks = 0; ks < 8; ks += 2) {
        int m = qt * 16 + lr;
        bf16x8 af0 = *reinterpret_cast<const bf16x8*>(
            smQ + m * 512 + ((((ks + 0) * 4 + lc) ^ (m & 15)) * 16));
        bf16x8 af1 = *reinterpret_cast<const bf16x8*>(
            smQ + m * 512 + ((((ks + 1) * 4 + lc) ^ (m & 15)) * 16));
        #pragma unroll
        for (int j = 0; j < 3; ++j) {
            int n = (ktb + j) * 16 + lr;
            bf16x8 bv0 = *reinterpret_cast<const bf16x8*>(
                smK + n * 512 + ((((ks + 0) * 4 + lc) ^ (n & 15)) * 16));
            bf16x8 bv1 = *reinterpret_cast<const bf16x8*>(
                smK + n * 512 + ((((ks + 1) * 4 + lc) ^ (n & 15)) * 16));
            acc[j]  = __builtin_amdgcn_mfma_f32_16x16x32_bf16(af0, bv0, acc[j], 0, 0, 0);
            acc2[j] = __builtin_amdgcn_mfma_f32_16x16x32_bf16(af1, bv1, acc2[j], 0, 0, 0);
        }
    }
    __syncthreads();

    #pragma unroll
    for (int j = 0; j < 3; ++j) {
        int col = (ktb + j) * 16 + lr;
        #pragma unroll
        for (int r = 0; r < 4; ++r) {
            int row = qt * 16 + lc * 4 + r;
            Sld[row * 97 + col] = acc[j][r] + acc2[j][r];
        }
    }
    __syncthreads();

    #pragma unroll
    for (int it = 0; it < 8; ++it) {
        int e = tid + it * 256;
        int i = e >> 6, l = e & 63;
        scores[(size_t)(t0 + i) * 64 + l] = Sld[i * 97 + i + l] * 0.0625f;
    }
}

// ---------------------------------------------------------------------------
// Top-8 select + softmax + V-sum. Top-8 via 64-lane bitonic sort
// (key = value desc, index asc -- identical order to jax.lax.top_k).
// ---------------------------------------------------------------------------
__global__ __launch_bounds__(256) void select_k(
    const float* __restrict__ scores, const u16* __restrict__ qkv,
    u16* __restrict__ summ)
{
    const int bid = blockIdx.x;                       // 2048 blocks
    const int sb  = (bid & 7) * 256 + (bid >> 3);     // bijective XCD swizzle
    const int m   = sb * 4 + (threadIdx.x >> 6);
    const int b = m >> 11;
    const int s = m & (S_ - 1);
    const int lane = threadIdx.x & 63;

    float v = (s - LB_ + lane >= 0) ? scores[(size_t)m * 64 + lane] : -INFINITY;
    int idx = lane;

    #pragma unroll
    for (int k = 2; k <= 64; k <<= 1) {
        #pragma unroll
        for (int j = k >> 1; j > 0; j >>= 1) {
            float ov = __shfl_xor(v, j);
            int   oi = __shfl_xor(idx, j);
            bool mineFirst = (v > ov) || (v == ov && idx < oi);
            bool lowLane  = (lane & j) == 0;
            bool dirFirst = (lane & k) == 0;
            bool keep = (lowLane == dirFirst) ? mineFirst : !mineFirst;
            if (!keep) { v = ov; idx = oi; }
        }
    }

    float vals[TOPK_]; int idxs[TOPK_];
    #pragma unroll
    for (int t = 0; t < TOPK_; ++t) {
        vals[t] = __shfl(v, t);
        idxs[t] = __shfl(idx, t);
    }

    const float mref = (vals[0] == -INFINITY) ? 0.f : vals[0];
    float e[TOPK_], ssum = 0.f;
    #pragma unroll
    for (int t = 0; t < TOPK_; ++t) { e[t] = expf(vals[t] - mref); ssum += e[t]; }
    const float inv = 1.f / fmaxf(ssum, 1e-30f);

    float o0 = 0.f, o1 = 0.f, o2 = 0.f, o3 = 0.f;
    #pragma unroll
    for (int t = 0; t < TOPK_; ++t) {
        float wt = e[t] * inv;
        int tok = s - LB_ + idxs[t];
        tok = min(max(tok, 0), S_ - 1);
        ushort4 vv = *reinterpret_cast<const ushort4*>(
            qkv + ((size_t)(b * S_) + tok) * 768 + 512 + lane * 4);
        o0 += wt * bf2f(vv.x);
        o1 += wt * bf2f(vv.y);
        o2 += wt * bf2f(vv.z);
        o3 += wt * bf2f(vv.w);
    }
    ushort4 pk;
    pk.x = f2bf(o0); pk.y = f2bf(o1); pk.z = f2bf(o2); pk.w = f2bf(o3);
    *reinterpret_cast<ushort4*>(summ + (size_t)m * DS_ + lane * 4) = pk;
}

// ---------------------------------------------------------------------------
// Merged prep: blocks 0..4095 cvt x->bf16; 4096..5183 weight transposes;
// 5184 qkv bias concat.
// ---------------------------------------------------------------------------
__global__ __launch_bounds__(256) void prep_all_k(
    const float* __restrict__ x,
    const float* __restrict__ Wi, const float* __restrict__ Wq,
    const float* __restrict__ Wk, const float* __restrict__ Wv,
    const float* __restrict__ Wp, const float* __restrict__ W1,
    const float* __restrict__ W2, const float* __restrict__ Wo,
    const float* __restrict__ bq, const float* __restrict__ bk,
    const float* __restrict__ bv,
    u16* __restrict__ xb,
    u16* __restrict__ Wit, u16* __restrict__ Wqkvt, u16* __restrict__ Wpt,
    u16* __restrict__ W1t, u16* __restrict__ W2t, u16* __restrict__ Wot,
    float* __restrict__ bqkv)
{
    const int bid0 = blockIdx.x;
    if (bid0 < 4096) {
        int i = (bid0 * 256 + threadIdx.x) * 8;
        float4 a = *reinterpret_cast<const float4*>(x + i);
        float4 b = *reinterpret_cast<const float4*>(x + i + 4);
        uint4 g;
        g.x = pack2(a.x, a.y); g.y = pack2(a.z, a.w);
        g.z = pack2(b.x, b.y); g.w = pack2(b.z, b.w);
        *reinterpret_cast<uint4*>(xb + i) = g;
        return;
    }
    const int bid = bid0 - 4096;
    if (bid >= 1088) {
        for (int i = threadIdx.x; i < 768; i += 256) {
            float v = (i < 256) ? bq[i] : (i < 512) ? bk[i - 256] : bv[i - 512];
            bqkv[i] = v;
        }
        return;
    }
    const float* in; u16* out; int K, N, t;
    if (bid < 256)      { in = Wi; out = Wit;             K = 1024; N = 256;  t = bid; }
    else if (bid < 320) { in = Wq; out = Wqkvt;           K = 256;  N = 256;  t = bid - 256; }
    else if (bid < 384) { in = Wk; out = Wqkvt + 256*256; K = 256;  N = 256;  t = bid - 320; }
    else if (bid < 448) { in = Wv; out = Wqkvt + 512*256; K = 256;  N = 256;  t = bid - 384; }
    else if (bid < 512) { in = Wp; out = Wpt;             K = 256;  N = 256;  t = bid - 448; }
    else if (bid < 768) { in = W1; out = W1t;             K = 1024; N = 256;  t = bid - 512; }
    else if (bid < 832) { in = W2; out = W2t;             K = 256;  N = 256;  t = bid - 768; }
    else                { in = Wo; out = Wot;             K = 256;  N = 1024; t = bid - 832; }
    const int tilesX = N >> 5;
    const int n0 = (t % tilesX) * 32, k0 = (t / tilesX) * 32;
    __shared__ float tl[32][33];
    const int cx = threadIdx.x & 31, cy = threadIdx.x >> 5;
    #pragma unroll
    for (int r = 0; r < 32; r += 8)
        tl[cy + r][cx] = in[(size_t)(k0 + cy + r) * N + n0 + cx];
    __syncthreads();
    #pragma unroll
    for (int r = 0; r < 32; r += 8)
        out[(size_t)(n0 + cy + r) * K + k0 + cx] = f2bf(tl[cx][cy + r]);
}

// ---------------------------------------------------------------------------
extern "C" void kernel_launch(void* const* d_in, const int* in_sizes, int n_in,
                              void* d_out, int out_size, void* d_ws, size_t ws_size,
                              hipStream_t stream)
{
    const float* x      = (const float*)d_in[0];
    const float* Wi     = (const float*)d_in[1];
    const float* bi     = (const float*)d_in[2];
    const float* conv_w = (const float*)d_in[3];
    const float* conv_b = (const float*)d_in[4];
    const float* Wp     = (const float*)d_in[5];
    const float* bp     = (const float*)d_in[6];
    const float* Wh     = (const float*)d_in[7];
    const float* bh     = (const float*)d_in[8];
    const float* Wq     = (const float*)d_in[9];
    const float* bq     = (const float*)d_in[10];
    const float* Wk     = (const float*)d_in[11];
    const float* bk     = (const float*)d_in[12];
    const float* Wv     = (const float*)d_in[13];
    const float* bv     = (const float*)d_in[14];
    const float* W1     = (const float*)d_in[15];
    const float* b1     = (const float*)d_in[16];
    const float* W2     = (const float*)d_in[17];
    const float* b2     = (const float*)d_in[18];
    const float* Wo     = (const float*)d_in[19];
    const float* bo     = (const float*)d_in[20];
    float* out = (float*)d_out;

    char* p = (char*)d_ws;
    auto alloc = [&](size_t bytes) { char* r = p; p += (bytes + 255) & ~(size_t)255; return r; };

    u16*  xb     = (u16*)alloc((size_t)BS_ * DM_ * 2);
    u16*  h      = (u16*)alloc((size_t)BS_ * DS_ * 2);
    u16*  mixed  = (u16*)alloc((size_t)BS_ * DS_ * 2);
    u16*  qkv    = (u16*)alloc((size_t)BS_ * 768 * 2);
    u16*  sm     = (u16*)alloc((size_t)BS_ * DS_ * 2);
    u16*  tb     = (u16*)alloc((size_t)BS_ * DS_ * 2);
    u16*  php    = (u16*)alloc((size_t)512 * DS_ * 2);
    float* gate  = (float*)alloc((size_t)BS_ * 4);
    float* scores= (float*)alloc((size_t)BS_ * 64 * 4);
    float* bqkv  = (float*)alloc(768 * 4);
    u16* Wit     = (u16*)alloc((size_t)256 * 1024 * 2);
    u16* Wqkvt   = (u16*)alloc((size_t)768 * 256 * 2);
    u16* Wpt     = (u16*)alloc((size_t)256 * 256 * 2);
    u16* W1t     = (u16*)alloc((size_t)256 * 1024 * 2);
    u16* W2t     = (u16*)alloc((size_t)256 * 256 * 2);
    u16* Wot     = (u16*)alloc((size_t)1024 * 256 * 2);

    dim3 blk(256);

    // ---- prep (cvt x + all weight transposes + bias concat) ----
    prep_all_k<<<5185, blk, 0, stream>>>(x, Wi, Wq, Wk, Wv, Wp, W1, W2, Wo,
                                         bq, bk, bv, xb,
                                         Wit, Wqkvt, Wpt, W1t, W2t, Wot, bqkv);

    // ---- forward ----
    // h = x @ Wi + bi   (K=1024 as 4 single-stage slabs)
    mm1024_k<0><<<512, blk, 0, stream>>>(xb, Wit, bi, h, DS_, 4, nullptr, nullptr);

    for (int step = 0; step < 2; ++step) {
        // packed: qkv single-stage GEMM (1536) + conv/pool/gate/php (512)
        step_a_k<<<2048, blk, 0, stream>>>(h, Wqkvt, bqkv, qkv,
                                           conv_w, conv_b, Wh, bh, Wpt, bp,
                                           mixed, php, gate);
        scores_k<<<256, blk, 0, stream>>>(qkv, scores);
        select_k<<<2048, blk, 0, stream>>>(scores, qkv, sm);
        mm_ui_k<<<512, blk, 0, stream>>>(h, mixed, php, sm, W1t, b1, tb);
        // h = h + (tanh(ui@W1+b1) @ W2 + b2) * gate   (K=256 single-stage)
        mm256_k<2><<<512, blk, 0, stream>>>(tb, W2t, b2, h, DS_, 4, h, gate);
    }

    // out = x + h @ Wo + bo   (K=256 single-stage)
    mm256_k<3><<<2048, blk, 0, stream>>>(h, Wot, bo, out, DM_, 16, xb, nullptr);
}

// Round 19
// 131.566 us; speedup vs baseline: 1.2241x; 1.0441x over previous
//
#include <hip/hip_runtime.h>
#include <math.h>

#define B_    4
#define S_    2048
#define BS_   8192       // B_*S_
#define DM_   1024
#define DS_   256
#define LB_   64
#define TOPK_ 8

typedef unsigned short u16;
typedef __bf16 bf16x8 __attribute__((ext_vector_type(8)));
typedef float  f32x4  __attribute__((ext_vector_type(4)));

static __device__ __forceinline__ u16 f2bf(float f) {
    union { float f; unsigned u; } a; a.f = f;
    unsigned u = a.u;
    unsigned r = u + 0x7FFFu + ((u >> 16) & 1u);   // RNE
    return (u16)(r >> 16);
}
static __device__ __forceinline__ float bf2f(u16 v) {
    union { unsigned u; float f; } a; a.u = ((unsigned)v) << 16; return a.f;
}
static __device__ __forceinline__ unsigned pack2(float a, float b) {
    return (unsigned)f2bf(a) | ((unsigned)f2bf(b) << 16);
}

// async global->LDS, 16B per lane; LDS dest = uniform base + lane*16
#define GLD16(g, l) __builtin_amdgcn_global_load_lds(                         \
    (const __attribute__((address_space(1))) void*)(g),                       \
    (__attribute__((address_space(3))) void*)(l), 16, 0, 0)

// ---------------------------------------------------------------------------
// Epilogue: EPI 0 -> C bf16 | 2 -> C bf16 = extra0_bf16 + val*extra1[m]
//           3 -> C f32 = extra0_bf16 + val.
// ---------------------------------------------------------------------------
template<int MF, int EPI>
__device__ __forceinline__ void epilogue(
    f32x4 (&acc)[MF][2], int bm, int bn, int wm, int wn, int lr, int lc,
    const float* __restrict__ bias, void* __restrict__ Cv, int N,
    const void* __restrict__ extra0v, const float* __restrict__ extra1)
{
    #pragma unroll
    for (int i = 0; i < MF; ++i) {
        #pragma unroll
        for (int j = 0; j < 2; ++j) {
            int col = bn + wn * 32 + j * 16 + lr;
            #pragma unroll
            for (int r = 0; r < 4; ++r) {
                int row = bm + wm * (MF * 16) + i * 16 + lc * 4 + r;
                float val = acc[i][j][r] + bias[col];
                if constexpr (EPI == 2) {
                    const u16* e0 = (const u16*)extra0v;
                    val = bf2f(e0[(size_t)row * N + col]) + val * extra1[row];
                    ((u16*)Cv)[(size_t)row * N + col] = f2bf(val);
                } else if constexpr (EPI == 3) {
                    const u16* e0 = (const u16*)extra0v;
                    ((float*)Cv)[(size_t)row * N + col] = bf2f(e0[(size_t)row * N + col]) + val;
                } else {
                    ((u16*)Cv)[(size_t)row * N + col] = f2bf(val);
                }
            }
        }
    }
}

// ---------------------------------------------------------------------------
// Shared compute over a staged 64x256 A-slab + 64x256 B-slab, split
// accumulators (even kg -> acc, odd kg -> acc2; caller merges).
// LDS rows 512B (32 granules of 16B), granule swizzle g^(row&15).
// ---------------------------------------------------------------------------
__device__ __forceinline__ void slab_mfma(
    unsigned char* smA, unsigned char* smB,
    f32x4 (&acc)[2][2], f32x4 (&acc2)[2][2],
    int wm, int wn, int lr, int lc)
{
    #pragma unroll
    for (int kg = 0; kg < 8; kg += 2) {
        bf16x8 af0[2], bf0[2], af1[2], bf1[2];
        #pragma unroll
        for (int i = 0; i < 2; ++i) {
            int m = wm * 32 + i * 16 + lr;
            af0[i] = *reinterpret_cast<const bf16x8*>(
                smA + m * 512 + ((((kg + 0) * 4 + lc) ^ (m & 15)) * 16));
            af1[i] = *reinterpret_cast<const bf16x8*>(
                smA + m * 512 + ((((kg + 1) * 4 + lc) ^ (m & 15)) * 16));
        }
        #pragma unroll
        for (int j = 0; j < 2; ++j) {
            int n = wn * 32 + j * 16 + lr;
            bf0[j] = *reinterpret_cast<const bf16x8*>(
                smB + n * 512 + ((((kg + 0) * 4 + lc) ^ (n & 15)) * 16));
            bf1[j] = *reinterpret_cast<const bf16x8*>(
                smB + n * 512 + ((((kg + 1) * 4 + lc) ^ (n & 15)) * 16));
        }
        #pragma unroll
        for (int i = 0; i < 2; ++i)
            #pragma unroll
            for (int j = 0; j < 2; ++j) {
                acc[i][j]  = __builtin_amdgcn_mfma_f32_16x16x32_bf16(
                    af0[i], bf0[j], acc[i][j], 0, 0, 0);
                acc2[i][j] = __builtin_amdgcn_mfma_f32_16x16x32_bf16(
                    af1[i], bf1[j], acc2[i][j], 0, 0, 0);
            }
    }
}

// simple (non-split) variant for the BN=128 path (keeps VGPR budget low)
__device__ __forceinline__ void slab_mfma1(
    unsigned char* smA, unsigned char* smB, f32x4 (&acc)[2][2],
    int wm, int wn, int lr, int lc)
{
    #pragma unroll
    for (int kg = 0; kg < 8; ++kg) {
        bf16x8 af[2], bfr[2];
        #pragma unroll
        for (int i = 0; i < 2; ++i) {
            int m = wm * 32 + i * 16 + lr;
            af[i] = *reinterpret_cast<const bf16x8*>(
                smA + m * 512 + (((kg * 4 + lc) ^ (m & 15)) * 16));
        }
        #pragma unroll
        for (int j = 0; j < 2; ++j) {
            int n = wn * 32 + j * 16 + lr;
            bfr[j] = *reinterpret_cast<const bf16x8*>(
                smB + n * 512 + (((kg * 4 + lc) ^ (n & 15)) * 16));
        }
        #pragma unroll
        for (int i = 0; i < 2; ++i)
            #pragma unroll
            for (int j = 0; j < 2; ++j)
                acc[i][j] = __builtin_amdgcn_mfma_f32_16x16x32_bf16(
                    af[i], bfr[j], acc[i][j], 0, 0, 0);
    }
}

// ---------------------------------------------------------------------------
// Single-stage full-K GEMM for K=256, BN=64 (R13 structure, measured best).
// ---------------------------------------------------------------------------
template<int EPI>
__device__ __forceinline__ void mm256_dev(
    unsigned char* smem, int id, int nb, int gx,
    const u16* __restrict__ A, const u16* __restrict__ Bt,
    const float* __restrict__ bias, void* __restrict__ Cv,
    int N, const void* __restrict__ extra0v, const float* __restrict__ extra1)
{
    unsigned char* smA = smem;
    unsigned char* smB = smem + 32768;

    const int per = nb >> 3;
    const int nid = (id & 7) * per + (id >> 3);   // bijective XCD chunking
    const int bx  = nid % gx, by = nid / gx;

    const int lane = threadIdx.x & 63, wid = threadIdx.x >> 6;
    const int wm   = wid >> 1, wn = wid & 1;
    const int bm   = by * 64, bn = bx * 64;
    const int lr   = lane & 15, lc = lane >> 4;
    const int lrow2 = lane >> 5;
    const int g_lin = lane & 31;

    #pragma unroll
    for (int t = 0; t < 8; ++t) {
        int rbase = wid * 16 + t * 2;
        int row   = rbase + lrow2;
        int gg    = g_lin ^ (row & 15);
        GLD16(A + (size_t)(bm + row) * 256 + gg * 8, smA + (size_t)rbase * 512);
    }
    #pragma unroll
    for (int t = 0; t < 8; ++t) {
        int rbase = wid * 16 + t * 2;
        int row   = rbase + lrow2;
        int gg    = g_lin ^ (row & 15);
        GLD16(Bt + (size_t)(bn + row) * 256 + gg * 8, smB + (size_t)rbase * 512);
    }
    __syncthreads();

    f32x4 acc[2][2] = {}, acc2[2][2] = {};
    slab_mfma(smA, smB, acc, acc2, wm, wn, lr, lc);
    #pragma unroll
    for (int i = 0; i < 2; ++i)
        #pragma unroll
        for (int j = 0; j < 2; ++j)
            acc[i][j] += acc2[i][j];

    epilogue<2, EPI>(acc, bm, bn, wm, wn, lr, lc, bias, Cv, N, extra0v, extra1);
}

template<int EPI>
__global__ __launch_bounds__(256) void mm256_k(
    const u16* __restrict__ A, const u16* __restrict__ Bt,
    const float* __restrict__ bias, void* __restrict__ Cv,
    int N, int gx,
    const void* __restrict__ extra0v, const float* __restrict__ extra1)
{
    __shared__ __align__(16) unsigned char smem[65536];
    mm256_dev<EPI>(smem, blockIdx.x, gridDim.x, gx, A, Bt, bias, Cv, N,
                   extra0v, extra1);
}

// ---------------------------------------------------------------------------
// K=256 GEMM, BN=128 with A-slab reuse: stage A once (32KB) + two sequential
// B column-halves (32KB buffer reused). 384 staged B/MFMA vs 512 at BN=64;
// grid-wide A-fetch halves. 3 barriers. Used for qkv (N=768) and Wo (N=1024).
// ---------------------------------------------------------------------------
template<int EPI>
__device__ __forceinline__ void mm256x2_dev(
    unsigned char* smem, int id, int nb, int gx2,
    const u16* __restrict__ A, const u16* __restrict__ Bt,
    const float* __restrict__ bias, void* __restrict__ Cv,
    int N, const void* __restrict__ extra0v, const float* __restrict__ extra1)
{
    unsigned char* smA = smem;
    unsigned char* smB = smem + 32768;

    const int per = nb >> 3;
    const int nid = (id & 7) * per + (id >> 3);   // bijective XCD chunking
    const int bx  = nid % gx2, by = nid / gx2;

    const int lane = threadIdx.x & 63, wid = threadIdx.x >> 6;
    const int wm   = wid >> 1, wn = wid & 1;
    const int bm   = by * 64, bn = bx * 128;
    const int lr   = lane & 15, lc = lane >> 4;
    const int lrow2 = lane >> 5;
    const int g_lin = lane & 31;

    // stage A (once) + B half 0
    #pragma unroll
    for (int t = 0; t < 8; ++t) {
        int rbase = wid * 16 + t * 2;
        int row   = rbase + lrow2;
        int gg    = g_lin ^ (row & 15);
        GLD16(A + (size_t)(bm + row) * 256 + gg * 8, smA + (size_t)rbase * 512);
    }
    #pragma unroll
    for (int t = 0; t < 8; ++t) {
        int rbase = wid * 16 + t * 2;
        int row   = rbase + lrow2;
        int gg    = g_lin ^ (row & 15);
        GLD16(Bt + (size_t)(bn + row) * 256 + gg * 8, smB + (size_t)rbase * 512);
    }
    __syncthreads();

    f32x4 acc0[2][2] = {};
    slab_mfma1(smA, smB, acc0, wm, wn, lr, lc);
    __syncthreads();   // all smB reads done before overwrite

    // stage B half 1 into the same buffer
    #pragma unroll
    for (int t = 0; t < 8; ++t) {
        int rbase = wid * 16 + t * 2;
        int row   = rbase + lrow2;
        int gg    = g_lin ^ (row & 15);
        GLD16(Bt + (size_t)(bn + 64 + row) * 256 + gg * 8,
              smB + (size_t)rbase * 512);
    }
    __syncthreads();

    f32x4 acc1[2][2] = {};
    slab_mfma1(smA, smB, acc1, wm, wn, lr, lc);

    epilogue<2, EPI>(acc0, bm, bn,      wm, wn, lr, lc, bias, Cv, N, extra0v, extra1);
    epilogue<2, EPI>(acc1, bm, bn + 64, wm, wn, lr, lc, bias, Cv, N, extra0v, extra1);
}

template<int EPI>
__global__ __launch_bounds__(256) void mm256x2_k(
    const u16* __restrict__ A, const u16* __restrict__ Bt,
    const float* __restrict__ bias, void* __restrict__ Cv,
    int N, int gx2,
    const void* __restrict__ extra0v, const float* __restrict__ extra1)
{
    __shared__ __align__(16) unsigned char smem[65536];
    mm256x2_dev<EPI>(smem, blockIdx.x, gridDim.x, gx2, A, Bt, bias, Cv, N,
                     extra0v, extra1);
}

// ---------------------------------------------------------------------------
// K=1024 GEMM as 4 sequential single-stage K=256 slabs. Used for Wi.
// ---------------------------------------------------------------------------
template<int EPI>
__global__ __launch_bounds__(256) void mm1024_k(
    const u16* __restrict__ A, const u16* __restrict__ Bt,
    const float* __restrict__ bias, void* __restrict__ Cv,
    int N, int gx,
    const void* __restrict__ extra0v, const float* __restrict__ extra1)
{
    __shared__ __align__(16) unsigned char smem[65536];
    unsigned char* smA = smem;
    unsigned char* smB = smem + 32768;

    const int nb  = gridDim.x;
    const int per = nb >> 3;
    const int id  = blockIdx.x;
    const int nid = (id & 7) * per + (id >> 3);
    const int bx  = nid % gx, by = nid / gx;

    const int lane = threadIdx.x & 63, wid = threadIdx.x >> 6;
    const int wm   = wid >> 1, wn = wid & 1;
    const int bm   = by * 64, bn = bx * 64;
    const int lr   = lane & 15, lc = lane >> 4;
    const int lrow2 = lane >> 5;
    const int g_lin = lane & 31;

    f32x4 acc[2][2] = {}, acc2[2][2] = {};

    #pragma unroll
    for (int s = 0; s < 4; ++s) {
        if (s) __syncthreads();   // previous slab's reads complete
        #pragma unroll
        for (int t = 0; t < 8; ++t) {
            int rbase = wid * 16 + t * 2;
            int row   = rbase + lrow2;
            int gg    = g_lin ^ (row & 15);
            GLD16(A + (size_t)(bm + row) * 1024 + s * 256 + gg * 8,
                  smA + (size_t)rbase * 512);
        }
        #pragma unroll
        for (int t = 0; t < 8; ++t) {
            int rbase = wid * 16 + t * 2;
            int row   = rbase + lrow2;
            int gg    = g_lin ^ (row & 15);
            GLD16(Bt + (size_t)(bn + row) * 1024 + s * 256 + gg * 8,
                  smB + (size_t)rbase * 512);
        }
        __syncthreads();
        slab_mfma(smA, smB, acc, acc2, wm, wn, lr, lc);
    }
    #pragma unroll
    for (int i = 0; i < 2; ++i)
        #pragma unroll
        for (int j = 0; j < 2; ++j)
            acc[i][j] += acc2[i][j];

    epilogue<2, EPI>(acc, bm, bn, wm, wn, lr, lc, bias, Cv, N, extra0v, extra1);
}

// ---------------------------------------------------------------------------
// ui-concat GEMM + tanh as 4 slabs; slab s's A-source = concat segment s
// (h | mixed | php(pool rows) | summ).
// ---------------------------------------------------------------------------
__global__ __launch_bounds__(256) void mm_ui_k(
    const u16* __restrict__ h, const u16* __restrict__ mixed,
    const u16* __restrict__ php, const u16* __restrict__ summ,
    const u16* __restrict__ W1t, const float* __restrict__ b1,
    u16* __restrict__ t)
{
    __shared__ __align__(16) unsigned char smem[65536];
    unsigned char* smA = smem;
    unsigned char* smB = smem + 32768;

    const int nb  = gridDim.x;
    const int per = nb >> 3;
    const int id  = blockIdx.x;
    const int nid = (id & 7) * per + (id >> 3);
    const int bx  = nid & 3, by = nid >> 2;

    const int lane = threadIdx.x & 63, wid = threadIdx.x >> 6;
    const int wm   = wid >> 1, wn = wid & 1;
    const int bm   = by * 64, bn = bx * 64;
    const int lr   = lane & 15, lc = lane >> 4;
    const int lrow2 = lane >> 5;
    const int g_lin = lane & 31;

    f32x4 acc[2][2] = {}, acc2[2][2] = {};

    #pragma unroll
    for (int s = 0; s < 4; ++s) {
        const u16* Asrc = (s == 0) ? h : (s == 1) ? mixed : (s == 2) ? php : summ;
        if (s) __syncthreads();
        #pragma unroll
        for (int tt = 0; tt < 8; ++tt) {
            int rbase = wid * 16 + tt * 2;
            int row   = rbase + lrow2;
            int gg    = g_lin ^ (row & 15);
            int rs    = bm + row;
            if (s == 2) rs >>= 4;
            GLD16(Asrc + (size_t)rs * 256 + gg * 8, smA + (size_t)rbase * 512);
        }
        #pragma unroll
        for (int tt = 0; tt < 8; ++tt) {
            int rbase = wid * 16 + tt * 2;
            int row   = rbase + lrow2;
            int gg    = g_lin ^ (row & 15);
            GLD16(W1t + (size_t)(bn + row) * 1024 + s * 256 + gg * 8,
                  smB + (size_t)rbase * 512);
        }
        __syncthreads();
        slab_mfma(smA, smB, acc, acc2, wm, wn, lr, lc);
    }

    #pragma unroll
    for (int i = 0; i < 2; ++i) {
        #pragma unroll
        for (int j = 0; j < 2; ++j) {
            int col = bn + wn * 32 + j * 16 + lr;
            #pragma unroll
            for (int r = 0; r < 4; ++r) {
                int row = bm + wm * 32 + i * 16 + lc * 4 + r;
                float v = acc[i][j][r] + acc2[i][j][r];
                t[(size_t)row * DS_ + col] = f2bf(tanhf(v + b1[col]));
            }
        }
    }
}

// ---------------------------------------------------------------------------
// Causal depthwise conv (K=5) + chunk mean + halt gate + fused php projection.
// ---------------------------------------------------------------------------
__device__ __forceinline__ void conv_dev(
    unsigned char* smem, int cid,
    const u16* __restrict__ h, const float* __restrict__ conv_w,
    const float* __restrict__ conv_b, const float* __restrict__ Wh,
    const float* __restrict__ bh, const u16* __restrict__ Wpt,
    const float* __restrict__ bp, u16* __restrict__ mixed,
    u16* __restrict__ php, float* __restrict__ gate)
{
    float* gpart = (float*)smem;            // [16][4]
    float* cm    = (float*)(smem + 256);    // [256]
    const int blk = (cid & 7) * 64 + (cid >> 3);   // XCD swizzle (8 x 64)
    const int d = threadIdx.x;
    const int b = blk >> 7;
    const int s0 = (blk & 127) * 16;
    const u16* hb = h + (size_t)b * S_ * DS_;
    u16* mb = mixed + (size_t)b * S_ * DS_;

    const float w0 = conv_w[0 * DS_ + d], w1 = conv_w[1 * DS_ + d],
                w2 = conv_w[2 * DS_ + d], w3 = conv_w[3 * DS_ + d],
                w4 = conv_w[4 * DS_ + d];
    const float cb = conv_b[d];
    const float whd = Wh[d * 3 + 2];

    float a0 = (s0 >= 4) ? bf2f(hb[(size_t)(s0 - 4) * DS_ + d]) : 0.f;
    float a1 = (s0 >= 3) ? bf2f(hb[(size_t)(s0 - 3) * DS_ + d]) : 0.f;
    float a2 = (s0 >= 2) ? bf2f(hb[(size_t)(s0 - 2) * DS_ + d]) : 0.f;
    float a3 = (s0 >= 1) ? bf2f(hb[(size_t)(s0 - 1) * DS_ + d]) : 0.f;

    float sum = 0.f;
    #pragma unroll
    for (int tt = 0; tt < 16; ++tt) {
        int s = s0 + tt;
        float cur = bf2f(hb[(size_t)s * DS_ + d]);
        mb[(size_t)s * DS_ + d] = f2bf(w0 * a0 + w1 * a1 + w2 * a2 + w3 * a3 + w4 * cur + cb);
        sum += cur;
        float g = cur * whd;
        #pragma unroll
        for (int off = 32; off; off >>= 1) g += __shfl_down(g, off);
        if ((d & 63) == 0) gpart[tt * 4 + (d >> 6)] = g;
        a0 = a1; a1 = a2; a2 = a3; a3 = cur;
    }
    cm[d] = sum * (1.f / 16.f);
    __syncthreads();
    if (d < 16) {
        float gg = gpart[d * 4 + 0] + gpart[d * 4 + 1] + gpart[d * 4 + 2] + gpart[d * 4 + 3];
        gate[(size_t)b * S_ + s0 + d] = 1.f / (1.f + expf(-(gg + bh[2])));
    }
    float accp = bp[d];
    const u16* wr = Wpt + (size_t)d * 256;
    #pragma unroll
    for (int k = 0; k < 256; k += 8) {
        bf16x8 w8 = *reinterpret_cast<const bf16x8*>(wr + k);
        accp += cm[k]     * (float)w8[0] + cm[k + 1] * (float)w8[1]
              + cm[k + 2] * (float)w8[2] + cm[k + 3] * (float)w8[3]
              + cm[k + 4] * (float)w8[4] + cm[k + 5] * (float)w8[5]
              + cm[k + 6] * (float)w8[6] + cm[k + 7] * (float)w8[7];
    }
    php[(size_t)blk * DS_ + d] = f2bf(accp);
}

// ---------------------------------------------------------------------------
// Packed launch: blocks 0..767 qkv GEMM (BN=128, K=256, N=768);
// 768..1279 conv+php.
// ---------------------------------------------------------------------------
__global__ __launch_bounds__(256) void step_a_k(
    const u16* __restrict__ h, const u16* __restrict__ Wqkvt,
    const float* __restrict__ bqkv, u16* __restrict__ qkv,
    const float* __restrict__ conv_w, const float* __restrict__ conv_b,
    const float* __restrict__ Wh, const float* __restrict__ bh,
    const u16* __restrict__ Wpt, const float* __restrict__ bp,
    u16* __restrict__ mixed, u16* __restrict__ php, float* __restrict__ gate)
{
    __shared__ __align__(16) unsigned char smem[65536];
    if (blockIdx.x < 768) {
        mm256x2_dev<0>(smem, blockIdx.x, 768, 6, h, Wqkvt, bqkv, qkv,
                       768, nullptr, nullptr);
    } else {
        conv_dev(smem, blockIdx.x - 768, h, conv_w, conv_b, Wh, bh,
                 Wpt, bp, mixed, php, gate);
    }
}

// ---------------------------------------------------------------------------
// Banded scores via MFMA, single-stage (3 barriers total), split accumulators.
// ---------------------------------------------------------------------------
__global__ __launch_bounds__(256) void scores_k(
    const u16* __restrict__ qkv, float* __restrict__ scores)
{
    __shared__ __align__(16) unsigned char smem[65536];  // Q 16KB | K 48KB
    unsigned char* smQ = smem;
    unsigned char* smK = smem + 16384;
    float* Sld = reinterpret_cast<float*>(smem);         // [32][97], aliases Q

    const int bid = blockIdx.x;                    // 256 blocks
    const int blk = (bid & 7) * 32 + (bid >> 3);   // XCD swizzle (8 x 32)
    const int t0 = blk * 32;
    const int b  = t0 >> 11;
    const int s0 = t0 & (S_ - 1);
    const int tid = threadIdx.x;
    const int lane = tid & 63, wid = tid >> 6;
    const int lr = lane & 15, lc = lane >> 4;
    const int qt  = wid & 1;
    const int ktb = (wid >> 1) * 3;
    const int lrow2 = lane >> 5;
    const int g_lin = lane & 31;

    #pragma unroll
    for (int t = 0; t < 4; ++t) {
        int rbase = wid * 8 + t * 2;
        int row   = rbase + lrow2;
        int gg    = g_lin ^ (row & 15);
        GLD16(qkv + (size_t)(t0 + row) * 768 + gg * 8,
              smQ + (size_t)rbase * 512);
    }
    #pragma unroll
    for (int t = 0; t < 12; ++t) {
        int rbase = wid * 24 + t * 2;
        int row   = rbase + lrow2;
        int krow  = s0 - 64 + row; if (krow < 0) krow = 0;
        int gg    = g_lin ^ (row & 15);
        GLD16(qkv + ((size_t)(b * S_) + krow) * 768 + 256 + gg * 8,
              smK + (size_t)rbase * 512);
    }
    __syncthreads();

    f32x4 acc[3] = {}, acc2[3] = {};
    #pragma unroll
    for (int ks = 0; ks < 8; ks += 2) {
        int m = qt * 16 + lr;
        bf16x8 af0 = *reinterpret_cast<const bf16x8*>(
            smQ + m * 512 + ((((ks + 0) * 4 + lc) ^ (m & 15)) * 16));
        bf16x8 af1 = *reinterpret_cast<const bf16x8*>(
            smQ + m * 512 + ((((ks + 1) * 4 + lc) ^ (m & 15)) * 16));
        #pragma unroll
        for (int j = 0; j < 3; ++j) {
            int n = (ktb + j) * 16 + lr;
            bf16x8 bv0 = *reinterpret_cast<const bf16x8*>(
                smK + n * 512 + ((((ks + 0) * 4 + lc) ^ (n & 15)) * 16));
            bf16x8 bv1 = *reinterpret_cast<const bf16x8*>(
                smK + n * 512 + ((((ks + 1) * 4 + lc) ^ (n & 15)) * 16));
            acc[j]  = __builtin_amdgcn_mfma_f32_16x16x32_bf16(af0, bv0, acc[j], 0, 0, 0);
            acc2[j] = __builtin_amdgcn_mfma_f32_16x16x32_bf16(af1, bv1, acc2[j], 0, 0, 0);
        }
    }
    __syncthreads();

    #pragma unroll
    for (int j = 0; j < 3; ++j) {
        int col = (ktb + j) * 16 + lr;
        #pragma unroll
        for (int r = 0; r < 4; ++r) {
            int row = qt * 16 + lc * 4 + r;
            Sld[row * 97 + col] = acc[j][r] + acc2[j][r];
        }
    }
    __syncthreads();

    #pragma unroll
    for (int it = 0; it < 8; ++it) {
        int e = tid + it * 256;
        int i = e >> 6, l = e & 63;
        scores[(size_t)(t0 + i) * 64 + l] = Sld[i * 97 + i + l] * 0.0625f;
    }
}

// ---------------------------------------------------------------------------
// Top-8 select + softmax + V-sum. Top-8 via 64-lane bitonic sort
// (key = value desc, index asc -- identical order to jax.lax.top_k).
// ---------------------------------------------------------------------------
__global__ __launch_bounds__(256) void select_k(
    const float* __restrict__ scores, const u16* __restrict__ qkv,
    u16* __restrict__ summ)
{
    const int bid = blockIdx.x;                       // 2048 blocks
    const int sb  = (bid & 7) * 256 + (bid >> 3);     // bijective XCD swizzle
    const int m   = sb * 4 + (threadIdx.x >> 6);
    const int b = m >> 11;
    const int s = m & (S_ - 1);
    const int lane = threadIdx.x & 63;

    float v = (s - LB_ + lane >= 0) ? scores[(size_t)m * 64 + lane] : -INFINITY;
    int idx = lane;

    #pragma unroll
    for (int k = 2; k <= 64; k <<= 1) {
        #pragma unroll
        for (int j = k >> 1; j > 0; j >>= 1) {
            float ov = __shfl_xor(v, j);
            int   oi = __shfl_xor(idx, j);
            bool mineFirst = (v > ov) || (v == ov && idx < oi);
            bool lowLane  = (lane & j) == 0;
            bool dirFirst = (lane & k) == 0;
            bool keep = (lowLane == dirFirst) ? mineFirst : !mineFirst;
            if (!keep) { v = ov; idx = oi; }
        }
    }

    float vals[TOPK_]; int idxs[TOPK_];
    #pragma unroll
    for (int t = 0; t < TOPK_; ++t) {
        vals[t] = __shfl(v, t);
        idxs[t] = __shfl(idx, t);
    }

    const float mref = (vals[0] == -INFINITY) ? 0.f : vals[0];
    float e[TOPK_], ssum = 0.f;
    #pragma unroll
    for (int t = 0; t < TOPK_; ++t) { e[t] = expf(vals[t] - mref); ssum += e[t]; }
    const float inv = 1.f / fmaxf(ssum, 1e-30f);

    float o0 = 0.f, o1 = 0.f, o2 = 0.f, o3 = 0.f;
    #pragma unroll
    for (int t = 0; t < TOPK_; ++t) {
        float wt = e[t] * inv;
        int tok = s - LB_ + idxs[t];
        tok = min(max(tok, 0), S_ - 1);
        ushort4 vv = *reinterpret_cast<const ushort4*>(
            qkv + ((size_t)(b * S_) + tok) * 768 + 512 + lane * 4);
        o0 += wt * bf2f(vv.x);
        o1 += wt * bf2f(vv.y);
        o2 += wt * bf2f(vv.z);
        o3 += wt * bf2f(vv.w);
    }
    ushort4 pk;
    pk.x = f2bf(o0); pk.y = f2bf(o1); pk.z = f2bf(o2); pk.w = f2bf(o3);
    *reinterpret_cast<ushort4*>(summ + (size_t)m * DS_ + lane * 4) = pk;
}

// ---------------------------------------------------------------------------
// Merged prep: blocks 0..4095 cvt x->bf16; 4096..5183 weight transposes;
// 5184 qkv bias concat.
// ---------------------------------------------------------------------------
__global__ __launch_bounds__(256) void prep_all_k(
    const float* __restrict__ x,
    const float* __restrict__ Wi, const float* __restrict__ Wq,
    const float* __restrict__ Wk, const float* __restrict__ Wv,
    const float* __restrict__ Wp, const float* __restrict__ W1,
    const float* __restrict__ W2, const float* __restrict__ Wo,
    const float* __restrict__ bq, const float* __restrict__ bk,
    const float* __restrict__ bv,
    u16* __restrict__ xb,
    u16* __restrict__ Wit, u16* __restrict__ Wqkvt, u16* __restrict__ Wpt,
    u16* __restrict__ W1t, u16* __restrict__ W2t, u16* __restrict__ Wot,
    float* __restrict__ bqkv)
{
    const int bid0 = blockIdx.x;
    if (bid0 < 4096) {
        int i = (bid0 * 256 + threadIdx.x) * 8;
        float4 a = *reinterpret_cast<const float4*>(x + i);
        float4 b = *reinterpret_cast<const float4*>(x + i + 4);
        uint4 g;
        g.x = pack2(a.x, a.y); g.y = pack2(a.z, a.w);
        g.z = pack2(b.x, b.y); g.w = pack2(b.z, b.w);
        *reinterpret_cast<uint4*>(xb + i) = g;
        return;
    }
    const int bid = bid0 - 4096;
    if (bid >= 1088) {
        for (int i = threadIdx.x; i < 768; i += 256) {
            float v = (i < 256) ? bq[i] : (i < 512) ? bk[i - 256] : bv[i - 512];
            bqkv[i] = v;
        }
        return;
    }
    const float* in; u16* out; int K, N, t;
    if (bid < 256)      { in = Wi; out = Wit;             K = 1024; N = 256;  t = bid; }
    else if (bid < 320) { in = Wq; out = Wqkvt;           K = 256;  N = 256;  t = bid - 256; }
    else if (bid < 384) { in = Wk; out = Wqkvt + 256*256; K = 256;  N = 256;  t = bid - 320; }
    else if (bid < 448) { in = Wv; out = Wqkvt + 512*256; K = 256;  N = 256;  t = bid - 384; }
    else if (bid < 512) { in = Wp; out = Wpt;             K = 256;  N = 256;  t = bid - 448; }
    else if (bid < 768) { in = W1; out = W1t;             K = 1024; N = 256;  t = bid - 512; }
    else if (bid < 832) { in = W2; out = W2t;             K = 256;  N = 256;  t = bid - 768; }
    else                { in = Wo; out = Wot;             K = 256;  N = 1024; t = bid - 832; }
    const int tilesX = N >> 5;
    const int n0 = (t % tilesX) * 32, k0 = (t / tilesX) * 32;
    __shared__ float tl[32][33];
    const int cx = threadIdx.x & 31, cy = threadIdx.x >> 5;
    #pragma unroll
    for (int r = 0; r < 32; r += 8)
        tl[cy + r][cx] = in[(size_t)(k0 + cy + r) * N + n0 + cx];
    __syncthreads();
    #pragma unroll
    for (int r = 0; r < 32; r += 8)
        out[(size_t)(n0 + cy + r) * K + k0 + cx] = f2bf(tl[cx][cy + r]);
}

// ---------------------------------------------------------------------------
extern "C" void kernel_launch(void* const* d_in, const int* in_sizes, int n_in,
                              void* d_out, int out_size, void* d_ws, size_t ws_size,
                              hipStream_t stream)
{
    const float* x      = (const float*)d_in[0];
    const float* Wi     = (const float*)d_in[1];
    const float* bi     = (const float*)d_in[2];
    const float* conv_w = (const float*)d_in[3];
    const float* conv_b = (const float*)d_in[4];
    const float* Wp     = (const float*)d_in[5];
    const float* bp     = (const float*)d_in[6];
    const float* Wh     = (const float*)d_in[7];
    const float* bh     = (const float*)d_in[8];
    const float* Wq     = (const float*)d_in[9];
    const float* bq     = (const float*)d_in[10];
    const float* Wk     = (const float*)d_in[11];
    const float* bk     = (const float*)d_in[12];
    const float* Wv     = (const float*)d_in[13];
    const float* bv     = (const float*)d_in[14];
    const float* W1     = (const float*)d_in[15];
    const float* b1     = (const float*)d_in[16];
    const float* W2     = (const float*)d_in[17];
    const float* b2     = (const float*)d_in[18];
    const float* Wo     = (const float*)d_in[19];
    const float* bo     = (const float*)d_in[20];
    float* out = (float*)d_out;

    char* p = (char*)d_ws;
    auto alloc = [&](size_t bytes) { char* r = p; p += (bytes + 255) & ~(size_t)255; return r; };

    u16*  xb     = (u16*)alloc((size_t)BS_ * DM_ * 2);
    u16*  h      = (u16*)alloc((size_t)BS_ * DS_ * 2);
    u16*  mixed  = (u16*)alloc((size_t)BS_ * DS_ * 2);
    u16*  qkv    = (u16*)alloc((size_t)BS_ * 768 * 2);
    u16*  sm     = (u16*)alloc((size_t)BS_ * DS_ * 2);
    u16*  tb     = (u16*)alloc((size_t)BS_ * DS_ * 2);
    u16*  php    = (u16*)alloc((size_t)512 * DS_ * 2);
    float* gate  = (float*)alloc((size_t)BS_ * 4);
    float* scores= (float*)alloc((size_t)BS_ * 64 * 4);
    float* bqkv  = (float*)alloc(768 * 4);
    u16* Wit     = (u16*)alloc((size_t)256 * 1024 * 2);
    u16* Wqkvt   = (u16*)alloc((size_t)768 * 256 * 2);
    u16* Wpt     = (u16*)alloc((size_t)256 * 256 * 2);
    u16* W1t     = (u16*)alloc((size_t)256 * 1024 * 2);
    u16* W2t     = (u16*)alloc((size_t)256 * 256 * 2);
    u16* Wot     = (u16*)alloc((size_t)1024 * 256 * 2);

    dim3 blk(256);

    // ---- prep (cvt x + all weight transposes + bias concat) ----
    prep_all_k<<<5185, blk, 0, stream>>>(x, Wi, Wq, Wk, Wv, Wp, W1, W2, Wo,
                                         bq, bk, bv, xb,
                                         Wit, Wqkvt, Wpt, W1t, W2t, Wot, bqkv);

    // ---- forward ----
    // h = x @ Wi + bi   (K=1024 as 4 single-stage slabs)
    mm1024_k<0><<<512, blk, 0, stream>>>(xb, Wit, bi, h, DS_, 4, nullptr, nullptr);

    for (int step = 0; step < 2; ++step) {
        // packed: qkv GEMM (768 blocks, BN=128) + conv/pool/gate/php (512)
        step_a_k<<<1280, blk, 0, stream>>>(h, Wqkvt, bqkv, qkv,
                                           conv_w, conv_b, Wh, bh, Wpt, bp,
                                           mixed, php, gate);
        scores_k<<<256, blk, 0, stream>>>(qkv, scores);
        select_k<<<2048, blk, 0, stream>>>(scores, qkv, sm);
        mm_ui_k<<<512, blk, 0, stream>>>(h, mixed, php, sm, W1t, b1, tb);
        // h = h + (tanh(ui@W1+b1) @ W2 + b2) * gate   (K=256 single-stage)
        mm256_k<2><<<512, blk, 0, stream>>>(tb, W2t, b2, h, DS_, 4, h, gate);
    }

    // out = x + h @ Wo + bo   (K=256, BN=128, 1024 blocks)
    mm256x2_k<3><<<1024, blk, 0, stream>>>(h, Wot, bo, out, DM_, 8, xb, nullptr);
}

// Round 20
// 131.497 us; speedup vs baseline: 1.2247x; 1.0005x over previous
//
#include <hip/hip_runtime.h>
#include <math.h>

#define B_    4
#define S_    2048
#define BS_   8192       // B_*S_
#define DM_   1024
#define DS_   256
#define LB_   64
#define TOPK_ 8

typedef unsigned short u16;
typedef __bf16 bf16x8 __attribute__((ext_vector_type(8)));
typedef float  f32x4  __attribute__((ext_vector_type(4)));

static __device__ __forceinline__ u16 f2bf(float f) {
    union { float f; unsigned u; } a; a.f = f;
    unsigned u = a.u;
    unsigned r = u + 0x7FFFu + ((u >> 16) & 1u);   // RNE
    return (u16)(r >> 16);
}
static __device__ __forceinline__ float bf2f(u16 v) {
    union { unsigned u; float f; } a; a.u = ((unsigned)v) << 16; return a.f;
}
static __device__ __forceinline__ unsigned pack2(float a, float b) {
    return (unsigned)f2bf(a) | ((unsigned)f2bf(b) << 16);
}

// async global->LDS, 16B per lane; LDS dest = uniform base + lane*16
#define GLD16(g, l) __builtin_amdgcn_global_load_lds(                         \
    (const __attribute__((address_space(1))) void*)(g),                       \
    (__attribute__((address_space(3))) void*)(l), 16, 0, 0)

// ---------------------------------------------------------------------------
// Epilogue: EPI 0 -> C bf16 | 2 -> C bf16 = extra0_bf16 + val*extra1[m]
//           3 -> C f32 = extra0_bf16 + val.
// ---------------------------------------------------------------------------
template<int MF, int EPI>
__device__ __forceinline__ void epilogue(
    f32x4 (&acc)[MF][2], int bm, int bn, int wm, int wn, int lr, int lc,
    const float* __restrict__ bias, void* __restrict__ Cv, int N,
    const void* __restrict__ extra0v, const float* __restrict__ extra1)
{
    #pragma unroll
    for (int i = 0; i < MF; ++i) {
        #pragma unroll
        for (int j = 0; j < 2; ++j) {
            int col = bn + wn * 32 + j * 16 + lr;
            #pragma unroll
            for (int r = 0; r < 4; ++r) {
                int row = bm + wm * (MF * 16) + i * 16 + lc * 4 + r;
                float val = acc[i][j][r] + bias[col];
                if constexpr (EPI == 2) {
                    const u16* e0 = (const u16*)extra0v;
                    val = bf2f(e0[(size_t)row * N + col]) + val * extra1[row];
                    ((u16*)Cv)[(size_t)row * N + col] = f2bf(val);
                } else if constexpr (EPI == 3) {
                    const u16* e0 = (const u16*)extra0v;
                    ((float*)Cv)[(size_t)row * N + col] = bf2f(e0[(size_t)row * N + col]) + val;
                } else {
                    ((u16*)Cv)[(size_t)row * N + col] = f2bf(val);
                }
            }
        }
    }
}

// ---------------------------------------------------------------------------
// Shared compute over a staged 64x256 A-slab + 64x256 B-slab, split
// accumulators (even kg -> acc, odd kg -> acc2; caller merges).
// LDS rows 512B (32 granules of 16B), granule swizzle g^(row&15).
// ---------------------------------------------------------------------------
__device__ __forceinline__ void slab_mfma(
    unsigned char* smA, unsigned char* smB,
    f32x4 (&acc)[2][2], f32x4 (&acc2)[2][2],
    int wm, int wn, int lr, int lc)
{
    #pragma unroll
    for (int kg = 0; kg < 8; kg += 2) {
        bf16x8 af0[2], bf0[2], af1[2], bf1[2];
        #pragma unroll
        for (int i = 0; i < 2; ++i) {
            int m = wm * 32 + i * 16 + lr;
            af0[i] = *reinterpret_cast<const bf16x8*>(
                smA + m * 512 + ((((kg + 0) * 4 + lc) ^ (m & 15)) * 16));
            af1[i] = *reinterpret_cast<const bf16x8*>(
                smA + m * 512 + ((((kg + 1) * 4 + lc) ^ (m & 15)) * 16));
        }
        #pragma unroll
        for (int j = 0; j < 2; ++j) {
            int n = wn * 32 + j * 16 + lr;
            bf0[j] = *reinterpret_cast<const bf16x8*>(
                smB + n * 512 + ((((kg + 0) * 4 + lc) ^ (n & 15)) * 16));
            bf1[j] = *reinterpret_cast<const bf16x8*>(
                smB + n * 512 + ((((kg + 1) * 4 + lc) ^ (n & 15)) * 16));
        }
        #pragma unroll
        for (int i = 0; i < 2; ++i)
            #pragma unroll
            for (int j = 0; j < 2; ++j) {
                acc[i][j]  = __builtin_amdgcn_mfma_f32_16x16x32_bf16(
                    af0[i], bf0[j], acc[i][j], 0, 0, 0);
                acc2[i][j] = __builtin_amdgcn_mfma_f32_16x16x32_bf16(
                    af1[i], bf1[j], acc2[i][j], 0, 0, 0);
            }
    }
}

// simple (non-split) variant for the BN=128 path (keeps VGPR budget low)
__device__ __forceinline__ void slab_mfma1(
    unsigned char* smA, unsigned char* smB, f32x4 (&acc)[2][2],
    int wm, int wn, int lr, int lc)
{
    #pragma unroll
    for (int kg = 0; kg < 8; ++kg) {
        bf16x8 af[2], bfr[2];
        #pragma unroll
        for (int i = 0; i < 2; ++i) {
            int m = wm * 32 + i * 16 + lr;
            af[i] = *reinterpret_cast<const bf16x8*>(
                smA + m * 512 + (((kg * 4 + lc) ^ (m & 15)) * 16));
        }
        #pragma unroll
        for (int j = 0; j < 2; ++j) {
            int n = wn * 32 + j * 16 + lr;
            bfr[j] = *reinterpret_cast<const bf16x8*>(
                smB + n * 512 + (((kg * 4 + lc) ^ (n & 15)) * 16));
        }
        #pragma unroll
        for (int i = 0; i < 2; ++i)
            #pragma unroll
            for (int j = 0; j < 2; ++j)
                acc[i][j] = __builtin_amdgcn_mfma_f32_16x16x32_bf16(
                    af[i], bfr[j], acc[i][j], 0, 0, 0);
    }
}

// ---------------------------------------------------------------------------
// Single-stage full-K GEMM for K=256, BN=64 (R13 structure, measured best).
// ---------------------------------------------------------------------------
template<int EPI>
__device__ __forceinline__ void mm256_dev(
    unsigned char* smem, int id, int nb, int gx,
    const u16* __restrict__ A, const u16* __restrict__ Bt,
    const float* __restrict__ bias, void* __restrict__ Cv,
    int N, const void* __restrict__ extra0v, const float* __restrict__ extra1)
{
    unsigned char* smA = smem;
    unsigned char* smB = smem + 32768;

    const int per = nb >> 3;
    const int nid = (id & 7) * per + (id >> 3);   // bijective XCD chunking
    const int bx  = nid % gx, by = nid / gx;

    const int lane = threadIdx.x & 63, wid = threadIdx.x >> 6;
    const int wm   = wid >> 1, wn = wid & 1;
    const int bm   = by * 64, bn = bx * 64;
    const int lr   = lane & 15, lc = lane >> 4;
    const int lrow2 = lane >> 5;
    const int g_lin = lane & 31;

    #pragma unroll
    for (int t = 0; t < 8; ++t) {
        int rbase = wid * 16 + t * 2;
        int row   = rbase + lrow2;
        int gg    = g_lin ^ (row & 15);
        GLD16(A + (size_t)(bm + row) * 256 + gg * 8, smA + (size_t)rbase * 512);
    }
    #pragma unroll
    for (int t = 0; t < 8; ++t) {
        int rbase = wid * 16 + t * 2;
        int row   = rbase + lrow2;
        int gg    = g_lin ^ (row & 15);
        GLD16(Bt + (size_t)(bn + row) * 256 + gg * 8, smB + (size_t)rbase * 512);
    }
    __syncthreads();

    f32x4 acc[2][2] = {}, acc2[2][2] = {};
    slab_mfma(smA, smB, acc, acc2, wm, wn, lr, lc);
    #pragma unroll
    for (int i = 0; i < 2; ++i)
        #pragma unroll
        for (int j = 0; j < 2; ++j)
            acc[i][j] += acc2[i][j];

    epilogue<2, EPI>(acc, bm, bn, wm, wn, lr, lc, bias, Cv, N, extra0v, extra1);
}

template<int EPI>
__global__ __launch_bounds__(256) void mm256_k(
    const u16* __restrict__ A, const u16* __restrict__ Bt,
    const float* __restrict__ bias, void* __restrict__ Cv,
    int N, int gx,
    const void* __restrict__ extra0v, const float* __restrict__ extra1)
{
    __shared__ __align__(16) unsigned char smem[65536];
    mm256_dev<EPI>(smem, blockIdx.x, gridDim.x, gx, A, Bt, bias, Cv, N,
                   extra0v, extra1);
}

// ---------------------------------------------------------------------------
// K=256 GEMM, BN=128 with A-slab reuse: stage A once (32KB) + two sequential
// B column-halves (32KB buffer reused). 384 staged B/MFMA vs 512 at BN=64;
// grid-wide A-fetch halves. 3 barriers. Used for qkv (N=768) and Wo (N=1024).
// ---------------------------------------------------------------------------
template<int EPI>
__device__ __forceinline__ void mm256x2_dev(
    unsigned char* smem, int id, int nb, int gx2,
    const u16* __restrict__ A, const u16* __restrict__ Bt,
    const float* __restrict__ bias, void* __restrict__ Cv,
    int N, const void* __restrict__ extra0v, const float* __restrict__ extra1)
{
    unsigned char* smA = smem;
    unsigned char* smB = smem + 32768;

    const int per = nb >> 3;
    const int nid = (id & 7) * per + (id >> 3);   // bijective XCD chunking
    const int bx  = nid % gx2, by = nid / gx2;

    const int lane = threadIdx.x & 63, wid = threadIdx.x >> 6;
    const int wm   = wid >> 1, wn = wid & 1;
    const int bm   = by * 64, bn = bx * 128;
    const int lr   = lane & 15, lc = lane >> 4;
    const int lrow2 = lane >> 5;
    const int g_lin = lane & 31;

    // stage A (once) + B half 0
    #pragma unroll
    for (int t = 0; t < 8; ++t) {
        int rbase = wid * 16 + t * 2;
        int row   = rbase + lrow2;
        int gg    = g_lin ^ (row & 15);
        GLD16(A + (size_t)(bm + row) * 256 + gg * 8, smA + (size_t)rbase * 512);
    }
    #pragma unroll
    for (int t = 0; t < 8; ++t) {
        int rbase = wid * 16 + t * 2;
        int row   = rbase + lrow2;
        int gg    = g_lin ^ (row & 15);
        GLD16(Bt + (size_t)(bn + row) * 256 + gg * 8, smB + (size_t)rbase * 512);
    }
    __syncthreads();

    f32x4 acc0[2][2] = {};
    slab_mfma1(smA, smB, acc0, wm, wn, lr, lc);
    __syncthreads();   // all smB reads done before overwrite

    // stage B half 1 into the same buffer
    #pragma unroll
    for (int t = 0; t < 8; ++t) {
        int rbase = wid * 16 + t * 2;
        int row   = rbase + lrow2;
        int gg    = g_lin ^ (row & 15);
        GLD16(Bt + (size_t)(bn + 64 + row) * 256 + gg * 8,
              smB + (size_t)rbase * 512);
    }
    __syncthreads();

    f32x4 acc1[2][2] = {};
    slab_mfma1(smA, smB, acc1, wm, wn, lr, lc);

    epilogue<2, EPI>(acc0, bm, bn,      wm, wn, lr, lc, bias, Cv, N, extra0v, extra1);
    epilogue<2, EPI>(acc1, bm, bn + 64, wm, wn, lr, lc, bias, Cv, N, extra0v, extra1);
}

template<int EPI>
__global__ __launch_bounds__(256) void mm256x2_k(
    const u16* __restrict__ A, const u16* __restrict__ Bt,
    const float* __restrict__ bias, void* __restrict__ Cv,
    int N, int gx2,
    const void* __restrict__ extra0v, const float* __restrict__ extra1)
{
    __shared__ __align__(16) unsigned char smem[65536];
    mm256x2_dev<EPI>(smem, blockIdx.x, gridDim.x, gx2, A, Bt, bias, Cv, N,
                     extra0v, extra1);
}

// ---------------------------------------------------------------------------
// K=1024 GEMM as 4 sequential single-stage K=256 slabs. Used for Wi.
// ---------------------------------------------------------------------------
template<int EPI>
__global__ __launch_bounds__(256) void mm1024_k(
    const u16* __restrict__ A, const u16* __restrict__ Bt,
    const float* __restrict__ bias, void* __restrict__ Cv,
    int N, int gx,
    const void* __restrict__ extra0v, const float* __restrict__ extra1)
{
    __shared__ __align__(16) unsigned char smem[65536];
    unsigned char* smA = smem;
    unsigned char* smB = smem + 32768;

    const int nb  = gridDim.x;
    const int per = nb >> 3;
    const int id  = blockIdx.x;
    const int nid = (id & 7) * per + (id >> 3);
    const int bx  = nid % gx, by = nid / gx;

    const int lane = threadIdx.x & 63, wid = threadIdx.x >> 6;
    const int wm   = wid >> 1, wn = wid & 1;
    const int bm   = by * 64, bn = bx * 64;
    const int lr   = lane & 15, lc = lane >> 4;
    const int lrow2 = lane >> 5;
    const int g_lin = lane & 31;

    f32x4 acc[2][2] = {}, acc2[2][2] = {};

    #pragma unroll
    for (int s = 0; s < 4; ++s) {
        if (s) __syncthreads();   // previous slab's reads complete
        #pragma unroll
        for (int t = 0; t < 8; ++t) {
            int rbase = wid * 16 + t * 2;
            int row   = rbase + lrow2;
            int gg    = g_lin ^ (row & 15);
            GLD16(A + (size_t)(bm + row) * 1024 + s * 256 + gg * 8,
                  smA + (size_t)rbase * 512);
        }
        #pragma unroll
        for (int t = 0; t < 8; ++t) {
            int rbase = wid * 16 + t * 2;
            int row   = rbase + lrow2;
            int gg    = g_lin ^ (row & 15);
            GLD16(Bt + (size_t)(bn + row) * 1024 + s * 256 + gg * 8,
                  smB + (size_t)rbase * 512);
        }
        __syncthreads();
        slab_mfma(smA, smB, acc, acc2, wm, wn, lr, lc);
    }
    #pragma unroll
    for (int i = 0; i < 2; ++i)
        #pragma unroll
        for (int j = 0; j < 2; ++j)
            acc[i][j] += acc2[i][j];

    epilogue<2, EPI>(acc, bm, bn, wm, wn, lr, lc, bias, Cv, N, extra0v, extra1);
}

// ---------------------------------------------------------------------------
// ui-concat GEMM + tanh as 4 slabs; slab s's A-source = concat segment s
// (h | mixed | php(pool rows) | summ).
// ---------------------------------------------------------------------------
__global__ __launch_bounds__(256) void mm_ui_k(
    const u16* __restrict__ h, const u16* __restrict__ mixed,
    const u16* __restrict__ php, const u16* __restrict__ summ,
    const u16* __restrict__ W1t, const float* __restrict__ b1,
    u16* __restrict__ t)
{
    __shared__ __align__(16) unsigned char smem[65536];
    unsigned char* smA = smem;
    unsigned char* smB = smem + 32768;

    const int nb  = gridDim.x;
    const int per = nb >> 3;
    const int id  = blockIdx.x;
    const int nid = (id & 7) * per + (id >> 3);
    const int bx  = nid & 3, by = nid >> 2;

    const int lane = threadIdx.x & 63, wid = threadIdx.x >> 6;
    const int wm   = wid >> 1, wn = wid & 1;
    const int bm   = by * 64, bn = bx * 64;
    const int lr   = lane & 15, lc = lane >> 4;
    const int lrow2 = lane >> 5;
    const int g_lin = lane & 31;

    f32x4 acc[2][2] = {}, acc2[2][2] = {};

    #pragma unroll
    for (int s = 0; s < 4; ++s) {
        const u16* Asrc = (s == 0) ? h : (s == 1) ? mixed : (s == 2) ? php : summ;
        if (s) __syncthreads();
        #pragma unroll
        for (int tt = 0; tt < 8; ++tt) {
            int rbase = wid * 16 + tt * 2;
            int row   = rbase + lrow2;
            int gg    = g_lin ^ (row & 15);
            int rs    = bm + row;
            if (s == 2) rs >>= 4;
            GLD16(Asrc + (size_t)rs * 256 + gg * 8, smA + (size_t)rbase * 512);
        }
        #pragma unroll
        for (int tt = 0; tt < 8; ++tt) {
            int rbase = wid * 16 + tt * 2;
            int row   = rbase + lrow2;
            int gg    = g_lin ^ (row & 15);
            GLD16(W1t + (size_t)(bn + row) * 1024 + s * 256 + gg * 8,
                  smB + (size_t)rbase * 512);
        }
        __syncthreads();
        slab_mfma(smA, smB, acc, acc2, wm, wn, lr, lc);
    }

    #pragma unroll
    for (int i = 0; i < 2; ++i) {
        #pragma unroll
        for (int j = 0; j < 2; ++j) {
            int col = bn + wn * 32 + j * 16 + lr;
            #pragma unroll
            for (int r = 0; r < 4; ++r) {
                int row = bm + wm * 32 + i * 16 + lc * 4 + r;
                float v = acc[i][j][r] + acc2[i][j][r];
                t[(size_t)row * DS_ + col] = f2bf(tanhf(v + b1[col]));
            }
        }
    }
}

// ---------------------------------------------------------------------------
// Causal depthwise conv (K=5) + chunk mean + halt gate + fused php projection.
// ---------------------------------------------------------------------------
__device__ __forceinline__ void conv_dev(
    unsigned char* smem, int cid,
    const u16* __restrict__ h, const float* __restrict__ conv_w,
    const float* __restrict__ conv_b, const float* __restrict__ Wh,
    const float* __restrict__ bh, const u16* __restrict__ Wpt,
    const float* __restrict__ bp, u16* __restrict__ mixed,
    u16* __restrict__ php, float* __restrict__ gate)
{
    float* gpart = (float*)smem;            // [16][4]
    float* cm    = (float*)(smem + 256);    // [256]
    const int blk = (cid & 7) * 64 + (cid >> 3);   // XCD swizzle (8 x 64)
    const int d = threadIdx.x;
    const int b = blk >> 7;
    const int s0 = (blk & 127) * 16;
    const u16* hb = h + (size_t)b * S_ * DS_;
    u16* mb = mixed + (size_t)b * S_ * DS_;

    const float w0 = conv_w[0 * DS_ + d], w1 = conv_w[1 * DS_ + d],
                w2 = conv_w[2 * DS_ + d], w3 = conv_w[3 * DS_ + d],
                w4 = conv_w[4 * DS_ + d];
    const float cb = conv_b[d];
    const float whd = Wh[d * 3 + 2];

    float a0 = (s0 >= 4) ? bf2f(hb[(size_t)(s0 - 4) * DS_ + d]) : 0.f;
    float a1 = (s0 >= 3) ? bf2f(hb[(size_t)(s0 - 3) * DS_ + d]) : 0.f;
    float a2 = (s0 >= 2) ? bf2f(hb[(size_t)(s0 - 2) * DS_ + d]) : 0.f;
    float a3 = (s0 >= 1) ? bf2f(hb[(size_t)(s0 - 1) * DS_ + d]) : 0.f;

    float sum = 0.f;
    #pragma unroll
    for (int tt = 0; tt < 16; ++tt) {
        int s = s0 + tt;
        float cur = bf2f(hb[(size_t)s * DS_ + d]);
        mb[(size_t)s * DS_ + d] = f2bf(w0 * a0 + w1 * a1 + w2 * a2 + w3 * a3 + w4 * cur + cb);
        sum += cur;
        float g = cur * whd;
        #pragma unroll
        for (int off = 32; off; off >>= 1) g += __shfl_down(g, off);
        if ((d & 63) == 0) gpart[tt * 4 + (d >> 6)] = g;
        a0 = a1; a1 = a2; a2 = a3; a3 = cur;
    }
    cm[d] = sum * (1.f / 16.f);
    __syncthreads();
    if (d < 16) {
        float gg = gpart[d * 4 + 0] + gpart[d * 4 + 1] + gpart[d * 4 + 2] + gpart[d * 4 + 3];
        gate[(size_t)b * S_ + s0 + d] = 1.f / (1.f + expf(-(gg + bh[2])));
    }
    float accp = bp[d];
    const u16* wr = Wpt + (size_t)d * 256;
    #pragma unroll
    for (int k = 0; k < 256; k += 8) {
        bf16x8 w8 = *reinterpret_cast<const bf16x8*>(wr + k);
        accp += cm[k]     * (float)w8[0] + cm[k + 1] * (float)w8[1]
              + cm[k + 2] * (float)w8[2] + cm[k + 3] * (float)w8[3]
              + cm[k + 4] * (float)w8[4] + cm[k + 5] * (float)w8[5]
              + cm[k + 6] * (float)w8[6] + cm[k + 7] * (float)w8[7];
    }
    php[(size_t)blk * DS_ + d] = f2bf(accp);
}

// ---------------------------------------------------------------------------
// Packed launch: blocks 0..767 qkv GEMM (BN=128, K=256, N=768);
// 768..1279 conv+php.
// ---------------------------------------------------------------------------
__global__ __launch_bounds__(256) void step_a_k(
    const u16* __restrict__ h, const u16* __restrict__ Wqkvt,
    const float* __restrict__ bqkv, u16* __restrict__ qkv,
    const float* __restrict__ conv_w, const float* __restrict__ conv_b,
    const float* __restrict__ Wh, const float* __restrict__ bh,
    const u16* __restrict__ Wpt, const float* __restrict__ bp,
    u16* __restrict__ mixed, u16* __restrict__ php, float* __restrict__ gate)
{
    __shared__ __align__(16) unsigned char smem[65536];
    if (blockIdx.x < 768) {
        mm256x2_dev<0>(smem, blockIdx.x, 768, 6, h, Wqkvt, bqkv, qkv,
                       768, nullptr, nullptr);
    } else {
        conv_dev(smem, blockIdx.x - 768, h, conv_w, conv_b, Wh, bh,
                 Wpt, bp, mixed, php, gate);
    }
}

// ---------------------------------------------------------------------------
// Banded scores via MFMA, single-stage (3 barriers total), split accumulators.
// ---------------------------------------------------------------------------
__global__ __launch_bounds__(256) void scores_k(
    const u16* __restrict__ qkv, float* __restrict__ scores)
{
    __shared__ __align__(16) unsigned char smem[65536];  // Q 16KB | K 48KB
    unsigned char* smQ = smem;
    unsigned char* smK = smem + 16384;
    float* Sld = reinterpret_cast<float*>(smem);         // [32][97], aliases Q

    const int bid = blockIdx.x;                    // 256 blocks
    const int blk = (bid & 7) * 32 + (bid >> 3);   // XCD swizzle (8 x 32)
    const int t0 = blk * 32;
    const int b  = t0 >> 11;
    const int s0 = t0 & (S_ - 1);
    const int tid = threadIdx.x;
    const int lane = tid & 63, wid = tid >> 6;
    const int lr = lane & 15, lc = lane >> 4;
    const int qt  = wid & 1;
    const int ktb = (wid >> 1) * 3;
    const int lrow2 = lane >> 5;
    const int g_lin = lane & 31;

    #pragma unroll
    for (int t = 0; t < 4; ++t) {
        int rbase = wid * 8 + t * 2;
        int row   = rbase + lrow2;
        int gg    = g_lin ^ (row & 15);
        GLD16(qkv + (size_t)(t0 + row) * 768 + gg * 8,
              smQ + (size_t)rbase * 512);
    }
    #pragma unroll
    for (int t = 0; t < 12; ++t) {
        int rbase = wid * 24 + t * 2;
        int row   = rbase + lrow2;
        int krow  = s0 - 64 + row; if (krow < 0) krow = 0;
        int gg    = g_lin ^ (row & 15);
        GLD16(qkv + ((size_t)(b * S_) + krow) * 768 + 256 + gg * 8,
              smK + (size_t)rbase * 512);
    }
    __syncthreads();

    f32x4 acc[3] = {}, acc2[3] = {};
    #pragma unroll
    for (int ks = 0; ks < 8; ks += 2) {
        int m = qt * 16 + lr;
        bf16x8 af0 = *reinterpret_cast<const bf16x8*>(
            smQ + m * 512 + ((((ks + 0) * 4 + lc) ^ (m & 15)) * 16));
        bf16x8 af1 = *reinterpret_cast<const bf16x8*>(
            smQ + m * 512 + ((((ks + 1) * 4 + lc) ^ (m & 15)) * 16));
        #pragma unroll
        for (int j = 0; j < 3; ++j) {
            int n = (ktb + j) * 16 + lr;
            bf16x8 bv0 = *reinterpret_cast<const bf16x8*>(
                smK + n * 512 + ((((ks + 0) * 4 + lc) ^ (n & 15)) * 16));
            bf16x8 bv1 = *reinterpret_cast<const bf16x8*>(
                smK + n * 512 + ((((ks + 1) * 4 + lc) ^ (n & 15)) * 16));
            acc[j]  = __builtin_amdgcn_mfma_f32_16x16x32_bf16(af0, bv0, acc[j], 0, 0, 0);
            acc2[j] = __builtin_amdgcn_mfma_f32_16x16x32_bf16(af1, bv1, acc2[j], 0, 0, 0);
        }
    }
    __syncthreads();

    #pragma unroll
    for (int j = 0; j < 3; ++j) {
        int col = (ktb + j) * 16 + lr;
        #pragma unroll
        for (int r = 0; r < 4; ++r) {
            int row = qt * 16 + lc * 4 + r;
            Sld[row * 97 + col] = acc[j][r] + acc2[j][r];
        }
    }
    __syncthreads();

    #pragma unroll
    for (int it = 0; it < 8; ++it) {
        int e = tid + it * 256;
        int i = e >> 6, l = e & 63;
        scores[(size_t)(t0 + i) * 64 + l] = Sld[i * 97 + i + l] * 0.0625f;
    }
}

// ---------------------------------------------------------------------------
// Top-8 select + softmax + V-sum. Top-8 via 64-lane bitonic sort
// (key = value desc, index asc -- identical order to jax.lax.top_k).
// ---------------------------------------------------------------------------
__global__ __launch_bounds__(256) void select_k(
    const float* __restrict__ scores, const u16* __restrict__ qkv,
    u16* __restrict__ summ)
{
    const int bid = blockIdx.x;                       // 2048 blocks
    const int sb  = (bid & 7) * 256 + (bid >> 3);     // bijective XCD swizzle
    const int m   = sb * 4 + (threadIdx.x >> 6);
    const int b = m >> 11;
    const int s = m & (S_ - 1);
    const int lane = threadIdx.x & 63;

    float v = (s - LB_ + lane >= 0) ? scores[(size_t)m * 64 + lane] : -INFINITY;
    int idx = lane;

    #pragma unroll
    for (int k = 2; k <= 64; k <<= 1) {
        #pragma unroll
        for (int j = k >> 1; j > 0; j >>= 1) {
            float ov = __shfl_xor(v, j);
            int   oi = __shfl_xor(idx, j);
            bool mineFirst = (v > ov) || (v == ov && idx < oi);
            bool lowLane  = (lane & j) == 0;
            bool dirFirst = (lane & k) == 0;
            bool keep = (lowLane == dirFirst) ? mineFirst : !mineFirst;
            if (!keep) { v = ov; idx = oi; }
        }
    }

    float vals[TOPK_]; int idxs[TOPK_];
    #pragma unroll
    for (int t = 0; t < TOPK_; ++t) {
        vals[t] = __shfl(v, t);
        idxs[t] = __shfl(idx, t);
    }

    const float mref = (vals[0] == -INFINITY) ? 0.f : vals[0];
    float e[TOPK_], ssum = 0.f;
    #pragma unroll
    for (int t = 0; t < TOPK_; ++t) { e[t] = expf(vals[t] - mref); ssum += e[t]; }
    const float inv = 1.f / fmaxf(ssum, 1e-30f);

    float o0 = 0.f, o1 = 0.f, o2 = 0.f, o3 = 0.f;
    #pragma unroll
    for (int t = 0; t < TOPK_; ++t) {
        float wt = e[t] * inv;
        int tok = s - LB_ + idxs[t];
        tok = min(max(tok, 0), S_ - 1);
        ushort4 vv = *reinterpret_cast<const ushort4*>(
            qkv + ((size_t)(b * S_) + tok) * 768 + 512 + lane * 4);
        o0 += wt * bf2f(vv.x);
        o1 += wt * bf2f(vv.y);
        o2 += wt * bf2f(vv.z);
        o3 += wt * bf2f(vv.w);
    }
    ushort4 pk;
    pk.x = f2bf(o0); pk.y = f2bf(o1); pk.z = f2bf(o2); pk.w = f2bf(o3);
    *reinterpret_cast<ushort4*>(summ + (size_t)m * DS_ + lane * 4) = pk;
}

// ---------------------------------------------------------------------------
// Merged prep: blocks 0..4095 cvt x->bf16; 4096..5183 weight transposes;
// 5184 qkv bias concat.
// ---------------------------------------------------------------------------
__global__ __launch_bounds__(256) void prep_all_k(
    const float* __restrict__ x,
    const float* __restrict__ Wi, const float* __restrict__ Wq,
    const float* __restrict__ Wk, const float* __restrict__ Wv,
    const float* __restrict__ Wp, const float* __restrict__ W1,
    const float* __restrict__ W2, const float* __restrict__ Wo,
    const float* __restrict__ bq, const float* __restrict__ bk,
    const float* __restrict__ bv,
    u16* __restrict__ xb,
    u16* __restrict__ Wit, u16* __restrict__ Wqkvt, u16* __restrict__ Wpt,
    u16* __restrict__ W1t, u16* __restrict__ W2t, u16* __restrict__ Wot,
    float* __restrict__ bqkv)
{
    const int bid0 = blockIdx.x;
    if (bid0 < 4096) {
        int i = (bid0 * 256 + threadIdx.x) * 8;
        float4 a = *reinterpret_cast<const float4*>(x + i);
        float4 b = *reinterpret_cast<const float4*>(x + i + 4);
        uint4 g;
        g.x = pack2(a.x, a.y); g.y = pack2(a.z, a.w);
        g.z = pack2(b.x, b.y); g.w = pack2(b.z, b.w);
        *reinterpret_cast<uint4*>(xb + i) = g;
        return;
    }
    const int bid = bid0 - 4096;
    if (bid >= 1088) {
        for (int i = threadIdx.x; i < 768; i += 256) {
            float v = (i < 256) ? bq[i] : (i < 512) ? bk[i - 256] : bv[i - 512];
            bqkv[i] = v;
        }
        return;
    }
    const float* in; u16* out; int K, N, t;
    if (bid < 256)      { in = Wi; out = Wit;             K = 1024; N = 256;  t = bid; }
    else if (bid < 320) { in = Wq; out = Wqkvt;           K = 256;  N = 256;  t = bid - 256; }
    else if (bid < 384) { in = Wk; out = Wqkvt + 256*256; K = 256;  N = 256;  t = bid - 320; }
    else if (bid < 448) { in = Wv; out = Wqkvt + 512*256; K = 256;  N = 256;  t = bid - 384; }
    else if (bid < 512) { in = Wp; out = Wpt;             K = 256;  N = 256;  t = bid - 448; }
    else if (bid < 768) { in = W1; out = W1t;             K = 1024; N = 256;  t = bid - 512; }
    else if (bid < 832) { in = W2; out = W2t;             K = 256;  N = 256;  t = bid - 768; }
    else                { in = Wo; out = Wot;             K = 256;  N = 1024; t = bid - 832; }
    const int tilesX = N >> 5;
    const int n0 = (t % tilesX) * 32, k0 = (t / tilesX) * 32;
    __shared__ float tl[32][33];
    const int cx = threadIdx.x & 31, cy = threadIdx.x >> 5;
    #pragma unroll
    for (int r = 0; r < 32; r += 8)
        tl[cy + r][cx] = in[(size_t)(k0 + cy + r) * N + n0 + cx];
    __syncthreads();
    #pragma unroll
    for (int r = 0; r < 32; r += 8)
        out[(size_t)(n0 + cy + r) * K + k0 + cx] = f2bf(tl[cx][cy + r]);
}

// ---------------------------------------------------------------------------
extern "C" void kernel_launch(void* const* d_in, const int* in_sizes, int n_in,
                              void* d_out, int out_size, void* d_ws, size_t ws_size,
                              hipStream_t stream)
{
    const float* x      = (const float*)d_in[0];
    const float* Wi     = (const float*)d_in[1];
    const float* bi     = (const float*)d_in[2];
    const float* conv_w = (const float*)d_in[3];
    const float* conv_b = (const float*)d_in[4];
    const float* Wp     = (const float*)d_in[5];
    const float* bp     = (const float*)d_in[6];
    const float* Wh     = (const float*)d_in[7];
    const float* bh     = (const float*)d_in[8];
    const float* Wq     = (const float*)d_in[9];
    const float* bq     = (const float*)d_in[10];
    const float* Wk     = (const float*)d_in[11];
    const float* bk     = (const float*)d_in[12];
    const float* Wv     = (const float*)d_in[13];
    const float* bv     = (const float*)d_in[14];
    const float* W1     = (const float*)d_in[15];
    const float* b1     = (const float*)d_in[16];
    const float* W2     = (const float*)d_in[17];
    const float* b2     = (const float*)d_in[18];
    const float* Wo     = (const float*)d_in[19];
    const float* bo     = (const float*)d_in[20];
    float* out = (float*)d_out;

    char* p = (char*)d_ws;
    auto alloc = [&](size_t bytes) { char* r = p; p += (bytes + 255) & ~(size_t)255; return r; };

    u16*  xb     = (u16*)alloc((size_t)BS_ * DM_ * 2);
    u16*  h      = (u16*)alloc((size_t)BS_ * DS_ * 2);
    u16*  mixed  = (u16*)alloc((size_t)BS_ * DS_ * 2);
    u16*  qkv    = (u16*)alloc((size_t)BS_ * 768 * 2);
    u16*  sm     = (u16*)alloc((size_t)BS_ * DS_ * 2);
    u16*  tb     = (u16*)alloc((size_t)BS_ * DS_ * 2);
    u16*  php    = (u16*)alloc((size_t)512 * DS_ * 2);
    float* gate  = (float*)alloc((size_t)BS_ * 4);
    float* scores= (float*)alloc((size_t)BS_ * 64 * 4);
    float* bqkv  = (float*)alloc(768 * 4);
    u16* Wit     = (u16*)alloc((size_t)256 * 1024 * 2);
    u16* Wqkvt   = (u16*)alloc((size_t)768 * 256 * 2);
    u16* Wpt     = (u16*)alloc((size_t)256 * 256 * 2);
    u16* W1t     = (u16*)alloc((size_t)256 * 1024 * 2);
    u16* W2t     = (u16*)alloc((size_t)256 * 256 * 2);
    u16* Wot     = (u16*)alloc((size_t)1024 * 256 * 2);

    dim3 blk(256);

    // ---- prep (cvt x + all weight transposes + bias concat) ----
    prep_all_k<<<5185, blk, 0, stream>>>(x, Wi, Wq, Wk, Wv, Wp, W1, W2, Wo,
                                         bq, bk, bv, xb,
                                         Wit, Wqkvt, Wpt, W1t, W2t, Wot, bqkv);

    // ---- forward ----
    // h = x @ Wi + bi   (K=1024 as 4 single-stage slabs)
    mm1024_k<0><<<512, blk, 0, stream>>>(xb, Wit, bi, h, DS_, 4, nullptr, nullptr);

    for (int step = 0; step < 2; ++step) {
        // packed: qkv GEMM (768 blocks, BN=128) + conv/pool/gate/php (512)
        step_a_k<<<1280, blk, 0, stream>>>(h, Wqkvt, bqkv, qkv,
                                           conv_w, conv_b, Wh, bh, Wpt, bp,
                                           mixed, php, gate);
        scores_k<<<256, blk, 0, stream>>>(qkv, scores);
        select_k<<<2048, blk, 0, stream>>>(scores, qkv, sm);
        mm_ui_k<<<512, blk, 0, stream>>>(h, mixed, php, sm, W1t, b1, tb);
        // h = h + (tanh(ui@W1+b1) @ W2 + b2) * gate   (K=256 single-stage)
        mm256_k<2><<<512, blk, 0, stream>>>(tb, W2t, b2, h, DS_, 4, h, gate);
    }

    // out = x + h @ Wo + bo   (K=256, BN=128, 1024 blocks)
    mm256x2_k<3><<<1024, blk, 0, stream>>>(h, Wot, bo, out, DM_, 8, xb, nullptr);
}